// Round 3
// baseline (7109.915 us; speedup 1.0000x reference)
//
#include <hip/hip_runtime.h>
#include <hip/hip_bf16.h>

typedef unsigned short ushort_t;
typedef unsigned int uint_t;

#define B_ 1024
#define N_ 64
#define H_ 128
#define L_ 4
#define K_ 16
#define R_ 20
#define NT 512
#define WS_PER_BLOCK 65536

__device__ __forceinline__ float bf2f(ushort_t u) {
    union { uint_t i; float f; } v; v.i = ((uint_t)u) << 16; return v.f;
}
__device__ __forceinline__ float lowbf(uint_t p) {
    union { uint_t i; float f; } v; v.i = p << 16; return v.f;
}
__device__ __forceinline__ float highbf(uint_t p) {
    union { uint_t i; float f; } v; v.i = p & 0xffff0000u; return v.f;
}
__device__ __forceinline__ ushort_t f2bf(float f) {
    uint_t u = __float_as_uint(f);
    uint_t r = (u + 0x7fffu + ((u >> 16) & 1u)) >> 16;
    return (ushort_t)r;
}
__device__ __forceinline__ uint_t pack2(float lo, float hi) {
    return (uint_t)f2bf(lo) | ((uint_t)f2bf(hi) << 16);
}
__device__ __forceinline__ float siluf(float x) { return x / (1.0f + __expf(-x)); }

__device__ __forceinline__ float ldx(const float* p, int i) { return p[i]; }
__device__ __forceinline__ float ldx(const ushort_t* p, int i) { return bf2f(p[i]); }
__device__ __forceinline__ void stx(float* p, int i, float v) { p[i] = v; }
__device__ __forceinline__ void stx(ushort_t* p, int i, float v) { p[i] = f2bf(v); }

// Static LDS: 65280 bytes. Hot reuse data only (activations live in ws).
struct __align__(16) Smem {
    float spos[N_ * 3];        //  768
    float env[N_ * K_];        // 4096
    float hmean[H_];           //  512
    float gvec[H_];            //  512
    ushort_t gm[N_ * H_];      // 16384 (neighbor-gather source, bf16)
    ushort_t rbf[N_ * K_ * R_];// 40960 (bf16)
    ushort_t idx[N_ * K_];     //  2048
};

// out[64][NF] = [ACC +=] ( SILU?( in1@W1 (+ in2@W2) + bias ) (+ resid) )
// in1/in2: [64][128] f32 or bf16 (global ws). W: global f32, row stride ldw.
// 4x4 register tile: 4 atom-rows share each float4 weight fetch.
template<int NF, bool ACC, bool SILU, bool HAS2, bool RES, typename TI1, typename TI2, typename TO>
__device__ __forceinline__ void gemm64(
    TO* __restrict__ out,
    const TI1* __restrict__ in1, const float* __restrict__ W1, int ldw1,
    const TI2* __restrict__ in2, const float* __restrict__ W2, int ldw2,
    const float* __restrict__ bias, const float* __restrict__ resid, int tid)
{
    constexpr int FG = NF / 4;
    for (int t = tid; t < 16 * FG; t += NT) {
        int ng = t / FG, fg = t - ng * FG;
        int n0 = ng * 4, f0 = fg * 4;
        float acc[4][4] = {{0.f}};
        {
            const float* w = W1 + f0;
            const TI1* x = in1 + n0 * H_;
            #pragma unroll 4
            for (int c = 0; c < H_; ++c) {
                float4 wv = *reinterpret_cast<const float4*>(w + (size_t)c * ldw1);
                #pragma unroll
                for (int i = 0; i < 4; ++i) {
                    float xv = ldx(x, i * H_ + c);
                    acc[i][0] = fmaf(xv, wv.x, acc[i][0]);
                    acc[i][1] = fmaf(xv, wv.y, acc[i][1]);
                    acc[i][2] = fmaf(xv, wv.z, acc[i][2]);
                    acc[i][3] = fmaf(xv, wv.w, acc[i][3]);
                }
            }
        }
        if (HAS2) {
            const float* w = W2 + f0;
            const TI2* x = in2 + n0 * H_;
            #pragma unroll 4
            for (int c = 0; c < H_; ++c) {
                float4 wv = *reinterpret_cast<const float4*>(w + (size_t)c * ldw2);
                #pragma unroll
                for (int i = 0; i < 4; ++i) {
                    float xv = ldx(x, i * H_ + c);
                    acc[i][0] = fmaf(xv, wv.x, acc[i][0]);
                    acc[i][1] = fmaf(xv, wv.y, acc[i][1]);
                    acc[i][2] = fmaf(xv, wv.z, acc[i][2]);
                    acc[i][3] = fmaf(xv, wv.w, acc[i][3]);
                }
            }
        }
        #pragma unroll
        for (int i = 0; i < 4; ++i) {
            #pragma unroll
            for (int j = 0; j < 4; ++j) {
                float a = acc[i][j];
                if (bias) a += bias[f0 + j];
                if (SILU) a = siluf(a);
                if (RES) a += resid[(n0 + i) * H_ + f0 + j];
                int o = (n0 + i) * NF + f0 + j;
                if (ACC) out[o] += a;   // only instantiated with TO=float
                else stx(out, o, a);
            }
        }
    }
}

extern "C" __global__ __launch_bounds__(NT, 2)
void md17_fused_kernel(
    const float* __restrict__ positions, const int* __restrict__ atomic_numbers,
    const float* __restrict__ atom_embed, const float* __restrict__ pos_W,
    const float* __restrict__ pos_b,
    const float* __restrict__ msg_W, const float* __restrict__ msg_b,
    const float* __restrict__ upd_W, const float* __restrict__ upd_b,
    const float* __restrict__ gself_W, const float* __restrict__ gmean_W,
    const float* __restrict__ g_b,
    const float* __restrict__ fus_W, const float* __restrict__ fus_b,
    const float* __restrict__ ln_g, const float* __restrict__ ln_b,
    const float* __restrict__ cb_W1, const float* __restrict__ cb_b1,
    const float* __restrict__ cb_W2, const float* __restrict__ cb_b2,
    const float* __restrict__ fo_W1, const float* __restrict__ fo_b1,
    const float* __restrict__ fo_W2, const float* __restrict__ fo_b2,
    char* __restrict__ ws, float* __restrict__ out)
{
    __shared__ Smem sm;
    const int b = blockIdx.x;
    const int tid = threadIdx.x;

    // per-block global scratch: h f32 [64][128], T1/T2 bf16 [64][128]
    char* wsb = ws + (size_t)b * WS_PER_BLOCK;
    float* h = (float*)wsb;
    ushort_t* T1 = (ushort_t*)(wsb + 32768);
    ushort_t* T2 = T1 + N_ * H_;

    // ---- positions -> LDS ----
    for (int t = tid; t < N_ * 3; t += NT) sm.spos[t] = positions[b * N_ * 3 + t];
    __syncthreads();

    // ---- kNN via picked-bitmask; d2 with explicit RN ops (match np f32) ----
    if (tid < N_) {
        int n = tid;
        float px = sm.spos[n * 3 + 0], py = sm.spos[n * 3 + 1], pz = sm.spos[n * 3 + 2];
        unsigned long long picked = 1ull << n;  // exclude self (== +eye*1e9)
        for (int k = 0; k < K_; ++k) {
            float best = 3e38f; int bi = 0;
            for (int m = 0; m < N_; ++m) {
                if ((picked >> m) & 1ull) continue;
                float dx = __fsub_rn(px, sm.spos[m * 3 + 0]);
                float dy = __fsub_rn(py, sm.spos[m * 3 + 1]);
                float dz = __fsub_rn(pz, sm.spos[m * 3 + 2]);
                float v = __fadd_rn(__fadd_rn(__fmul_rn(dx, dx), __fmul_rn(dy, dy)), __fmul_rn(dz, dz));
                if (v < best) { best = v; bi = m; }   // strict < => lowest index on ties, like top_k
            }
            picked |= 1ull << bi;
            sm.idx[n * K_ + k] = (ushort_t)bi;
            float dd = sqrtf(fmaxf(best, 1e-12f));
            float e = 0.0f;
            if (dd < 5.0f) e = 0.5f * (cosf(3.14159265358979323846f * dd * 0.2f) + 1.0f);
            sm.env[n * K_ + k] = e;
            #pragma unroll
            for (int r = 0; r < R_; ++r) {
                float cc = (float)((double)r * (5.0 / 19.0));
                float t2 = dd - cc;
                sm.rbf[(n * K_ + k) * R_ + r] = f2bf(expf(-10.0f * t2 * t2));
            }
        }
    }
    __syncthreads();

    // ---- embeddings: h = [atom_embed[type] (32) || pos@pos_W + pos_b (96)] ----
    for (int t = tid; t < N_ * H_; t += NT) {
        int n = t >> 7, f = t & 127;
        float v;
        if (f < 32) {
            v = atom_embed[atomic_numbers[b * N_ + n] * 32 + f];
        } else {
            int j = f - 32;
            v = pos_b[j];
            #pragma unroll
            for (int c = 0; c < 3; ++c)
                v = fmaf(sm.spos[n * 3 + c], pos_W[c * 96 + j], v);
        }
        h[t] = v;
    }
    __syncthreads();

    for (int l = 0; l < L_; ++l) {
        const float* mW  = msg_W + l * 276 * H_;
        const float* mb  = msg_b + l * H_;
        const float* uW  = upd_W + l * H_ * H_;
        const float* ub  = upd_b + l * H_;
        const float* gsW = gself_W + l * H_ * H_;
        const float* gmW = gmean_W + l * H_ * H_;
        const float* gb  = g_b + l * H_;
        const float* fW  = fus_W + l * 2 * H_ * H_;
        const float* fb  = fus_b + l * H_;
        const float* lg  = ln_g + l * H_;
        const float* lb  = ln_b + l * H_;
        const float* c1W = cb_W1 + l * H_ * 4 * H_;
        const float* c1b = cb_b1 + l * 4 * H_;
        const float* c2W = cb_W2 + l * 4 * H_ * H_;
        const float* c2b = cb_b2 + l * H_;

        // hmean over atoms (f32)
        if (tid < H_) {
            float s = 0.f;
            for (int n = 0; n < N_; ++n) s += h[n * H_ + tid];
            sm.hmean[tid] = s * (1.0f / 64.0f);
        }
        __syncthreads();
        // gvec = hmean @ gmean_W + g_b (tiny GEMV)
        if (tid < H_) {
            float s = gb[tid];
            for (int c = 0; c < H_; ++c) s = fmaf(sm.hmean[c], gmW[c * H_ + tid], s);
            sm.gvec[tid] = s;
        }
        // msg linearity split: Ai = h@Wi + mb -> T1 ; Gm = h@Wj -> LDS
        gemm64<128, false, false, false, false>(T1, h, mW, H_, (const float*)nullptr, nullptr, 0, mb, nullptr, tid);
        gemm64<128, false, false, false, false>(sm.gm, h, mW + 128 * H_, H_, (const float*)nullptr, nullptr, 0, nullptr, nullptr, tid);
        __syncthreads();

        // msum: T1[n][f] = sum_k silu(Ai + Gm[idx] + rbf@Wr) * env   (f32 accum)
        {
            const float* rW = mW + 256 * H_; // [20][128]
            for (int t = tid; t < N_ * 32; t += NT) {
                int n = t >> 5, f0 = (t & 31) << 2;
                float4 wr[R_];
                #pragma unroll
                for (int r = 0; r < R_; ++r)
                    wr[r] = *reinterpret_cast<const float4*>(rW + r * H_ + f0);
                uint2 aiu = *reinterpret_cast<const uint2*>(T1 + n * H_ + f0);
                float ai0 = lowbf(aiu.x), ai1 = highbf(aiu.x), ai2 = lowbf(aiu.y), ai3 = highbf(aiu.y);
                float s0 = 0.f, s1 = 0.f, s2 = 0.f, s3 = 0.f;
                for (int k = 0; k < K_; ++k) {
                    int j = sm.idx[n * K_ + k];
                    float e = sm.env[n * K_ + k];
                    const ushort_t* rb = sm.rbf + (n * K_ + k) * R_;
                    float r0 = 0.f, r1 = 0.f, r2 = 0.f, r3 = 0.f;
                    #pragma unroll
                    for (int r = 0; r < R_; ++r) {
                        float rv = bf2f(rb[r]);
                        r0 = fmaf(rv, wr[r].x, r0);
                        r1 = fmaf(rv, wr[r].y, r1);
                        r2 = fmaf(rv, wr[r].z, r2);
                        r3 = fmaf(rv, wr[r].w, r3);
                    }
                    uint2 gmu = *reinterpret_cast<const uint2*>(sm.gm + j * H_ + f0);
                    float p0 = ai0 + lowbf(gmu.x) + r0;
                    float p1 = ai1 + highbf(gmu.x) + r1;
                    float p2 = ai2 + lowbf(gmu.y) + r2;
                    float p3 = ai3 + highbf(gmu.y) + r3;
                    s0 = fmaf(siluf(p0), e, s0);
                    s1 = fmaf(siluf(p1), e, s1);
                    s2 = fmaf(siluf(p2), e, s2);
                    s3 = fmaf(siluf(p3), e, s3);
                }
                uint2 o;
                o.x = pack2(s0, s1);
                o.y = pack2(s2, s3);
                *reinterpret_cast<uint2*>(T1 + n * H_ + f0) = o;
            }
        }
        __syncthreads();

        // local = h + silu(msum @ upd_W + ub) -> T2
        gemm64<128, false, true, false, true>(T2, T1, uW, H_, (const float*)nullptr, nullptr, 0, ub, h, tid);
        __syncthreads();
        // glob = silu(h @ gself_W + gvec) -> T1  (msum dead)
        gemm64<128, false, true, false, false>(T1, h, gsW, H_, (const float*)nullptr, nullptr, 0, sm.gvec, nullptr, tid);
        __syncthreads();
        // fused = silu(local @ fW_top + glob @ fW_bot + fb) -> h (old h dead)
        gemm64<128, false, true, true, false>(h, T2, fW, H_, T1, fW + 128 * H_, H_, fb, nullptr, tid);
        __syncthreads();

        // LN(fused) -> T2 (bf16) ; h = fused + cb_b2 (accumulator init, f32)
        {
            int wv = tid >> 6, lane = tid & 63;
            for (int n = wv; n < N_; n += 8) {
                float x0 = h[n * H_ + lane];
                float x1 = h[n * H_ + 64 + lane];
                float s = x0 + x1;
                float ss = x0 * x0 + x1 * x1;
                #pragma unroll
                for (int o = 32; o > 0; o >>= 1) {
                    s += __shfl_xor(s, o);
                    ss += __shfl_xor(ss, o);
                }
                float mu = s * (1.0f / 128.0f);
                float var = ss * (1.0f / 128.0f) - mu * mu;
                float rs = rsqrtf(var + 1e-5f);
                T2[n * H_ + lane]      = f2bf((x0 - mu) * rs * lg[lane] + lb[lane]);
                T2[n * H_ + 64 + lane] = f2bf((x1 - mu) * rs * lg[64 + lane] + lb[64 + lane]);
                h[n * H_ + lane]      = x0 + c2b[lane];
                h[n * H_ + 64 + lane] = x1 + c2b[64 + lane];
            }
        }
        __syncthreads();

        // Clifford MLP: 4 chunks of the 512 hidden dim
        for (int j = 0; j < 4; ++j) {
            gemm64<128, false, true, false, false>(T1, T2, c1W + j * H_, 4 * H_, (const float*)nullptr, nullptr, 0, c1b + j * H_, nullptr, tid);
            __syncthreads();
            gemm64<128, true, false, false, false>(h, T1, c2W + j * H_ * H_, H_, (const float*)nullptr, nullptr, 0, nullptr, nullptr, tid);
            __syncthreads();
        }
    }

    // ---- force head ----
    gemm64<128, false, true, false, false>(T1, h, fo_W1, H_, (const float*)nullptr, nullptr, 0, fo_b1, nullptr, tid);
    __syncthreads();
    for (int t = tid; t < N_ * 3; t += NT) {
        int n = t / 3, j = t - n * 3;
        float s = fo_b2[j];
        for (int c = 0; c < H_; ++c)
            s = fmaf(bf2f(T1[n * H_ + c]), fo_W2[c * 3 + j], s);
        out[b * N_ * 3 + t] = s;
    }
}

extern "C" void kernel_launch(void* const* d_in, const int* in_sizes, int n_in,
                              void* d_out, int out_size, void* d_ws, size_t ws_size,
                              hipStream_t stream) {
    (void)in_sizes; (void)n_in; (void)out_size; (void)ws_size;
    md17_fused_kernel<<<B_, NT, 0, stream>>>(
        (const float*)d_in[0], (const int*)d_in[1],
        (const float*)d_in[2], (const float*)d_in[3], (const float*)d_in[4],
        (const float*)d_in[5], (const float*)d_in[6],
        (const float*)d_in[7], (const float*)d_in[8],
        (const float*)d_in[9], (const float*)d_in[10], (const float*)d_in[11],
        (const float*)d_in[12], (const float*)d_in[13],
        (const float*)d_in[14], (const float*)d_in[15],
        (const float*)d_in[16], (const float*)d_in[17],
        (const float*)d_in[18], (const float*)d_in[19],
        (const float*)d_in[20], (const float*)d_in[21],
        (const float*)d_in[22], (const float*)d_in[23],
        (char*)d_ws, (float*)d_out);
}

// Round 4
// 3361.489 us; speedup vs baseline: 2.1151x; 2.1151x over previous
//
#include <hip/hip_runtime.h>

typedef unsigned short ushort_t;
typedef unsigned int uint_t;
typedef __attribute__((ext_vector_type(8))) short short8;
typedef __attribute__((ext_vector_type(4))) float f32x4;

#define B_ 1024
#define N_ 64
#define H_ 128
#define L_ 4
#define K_ 16
#define R_ 20
#define NT 512
#define WS_PER_BLOCK 65536

__device__ __forceinline__ ushort_t f2bf(float f) {
    uint_t u = __float_as_uint(f);
    uint_t r = (u + 0x7fffu + ((u >> 16) & 1u)) >> 16;
    return (ushort_t)r;
}
__device__ __forceinline__ float bf2f(ushort_t u) {
    union { uint_t i; float f; } v; v.i = ((uint_t)u) << 16; return v.f;
}
__device__ __forceinline__ float lowbf(uint_t p) {
    union { uint_t i; float f; } v; v.i = p << 16; return v.f;
}
__device__ __forceinline__ float highbf(uint_t p) {
    union { uint_t i; float f; } v; v.i = p & 0xffff0000u; return v.f;
}
__device__ __forceinline__ uint_t pack2(float lo, float hi) {
    return (uint_t)f2bf(lo) | ((uint_t)f2bf(hi) << 16);
}
__device__ __forceinline__ float siluf(float x) { return x / (1.0f + __expf(-x)); }

// swizzled element index: 16B-chunk c of row m stored at chunk c ^ (m&7).
// -> ds_read_b128 of a frag (lanes differ in m) spreads across banks (<=2-way).
__device__ __forceinline__ int sidx(int m, int k) {
    return m * H_ + (((k >> 3) ^ (m & 7)) << 3) + (k & 7);
}
__device__ __forceinline__ int fragoff(int m, int ch) {
    return m * H_ + ((ch ^ (m & 7)) << 3);
}

// Static LDS: 65280 B (<=64KB) -> 2 blocks/CU.
struct __align__(16) Smem {
    ushort_t Ha[N_ * H_];   // 16384  h (bf16 image, swizzled)
    ushort_t T1[N_ * H_];   // 16384
    ushort_t T2[N_ * H_];   // 16384
    ushort_t WT[32 * H_];   //  8192  staged W^T chunk [n=32][k=128], swizzled
    float spos[N_ * 3];     //   768
    float env[N_ * K_];     //  4096
    float hmean[H_];        //   512
    float gvec[H_];         //   512
    ushort_t idx[N_ * K_];  //  2048
};

// EPI: 0 = +bias (Ai) | 1 = raw (Gm) | 2 = silu(+bias) | 3 = hws + silu(+bias) | 4 = silu(+bias), also write hws
template<int EPI, bool DUAL>
__device__ __forceinline__ void do_gemm(
    Smem* sm, const ushort_t* X, const ushort_t* X2,
    const float* Wg, const float* Wg2, int ldw,
    const float* bias, float* hws, ushort_t* dst, int tid)
{
    const int wave = tid >> 6, lane = tid & 63;
    const int quad = lane >> 4, l15 = lane & 15;
    const int Mt = wave >> 1;
    const int mrow = Mt * 16 + l15;
    const int nl = (wave & 1) * 16 + l15;
    short8 a[4], a2[4];
    for (int s = 0; s < 4; ++s) {
        __syncthreads();  // WT free (prev stage / prev GEMM reads done)
        for (int t = tid; t < 32 * H_; t += NT) {
            int k = t >> 5, n = t & 31;
            sm->WT[n * H_ + (((k >> 3) ^ (n & 7)) << 3) + (k & 7)] =
                f2bf(Wg[(size_t)k * ldw + s * 32 + n]);
        }
        __syncthreads();
        if (s == 0) {   // input X/X2 guaranteed stable after the barrier above
            #pragma unroll
            for (int kc = 0; kc < 4; ++kc) {
                a[kc] = *(const short8*)&X[fragoff(mrow, kc * 4 + quad)];
                if (DUAL) a2[kc] = *(const short8*)&X2[fragoff(mrow, kc * 4 + quad)];
            }
        }
        f32x4 acc = {0.f, 0.f, 0.f, 0.f};
        #pragma unroll
        for (int kc = 0; kc < 4; ++kc) {
            short8 bf = *(const short8*)&sm->WT[fragoff(nl, kc * 4 + quad)];
            acc = __builtin_amdgcn_mfma_f32_16x16x32_bf16(a[kc], bf, acc, 0, 0, 0);
        }
        if (DUAL) {
            __syncthreads();
            for (int t = tid; t < 32 * H_; t += NT) {
                int k = t >> 5, n = t & 31;
                sm->WT[n * H_ + (((k >> 3) ^ (n & 7)) << 3) + (k & 7)] =
                    f2bf(Wg2[(size_t)k * ldw + s * 32 + n]);
            }
            __syncthreads();
            #pragma unroll
            for (int kc = 0; kc < 4; ++kc) {
                short8 bf = *(const short8*)&sm->WT[fragoff(nl, kc * 4 + quad)];
                acc = __builtin_amdgcn_mfma_f32_16x16x32_bf16(a2[kc], bf, acc, 0, 0, 0);
            }
        }
        #pragma unroll
        for (int r = 0; r < 4; ++r) {
            int row = Mt * 16 + quad * 4 + r;
            int col = s * 32 + nl;
            float v = acc[r];
            if (EPI == 0) v += bias[col];
            if (EPI == 2) v = siluf(v + bias[col]);
            if (EPI == 3) v = hws[row * H_ + col] + siluf(v + bias[col]);
            if (EPI == 4) { v = siluf(v + bias[col]); hws[row * H_ + col] = v; }
            dst[sidx(row, col)] = f2bf(v);
        }
    }
}

// persistent-accumulator GEMM (cb_W2 K-chunk): acc2[s] accumulates across calls
__device__ __forceinline__ void gemm_acc(
    Smem* sm, const ushort_t* X, const float* Wg, f32x4 acc2[4], int tid)
{
    const int wave = tid >> 6, lane = tid & 63;
    const int quad = lane >> 4, l15 = lane & 15;
    const int Mt = wave >> 1;
    const int mrow = Mt * 16 + l15;
    const int nl = (wave & 1) * 16 + l15;
    short8 a[4];
    for (int s = 0; s < 4; ++s) {
        __syncthreads();
        for (int t = tid; t < 32 * H_; t += NT) {
            int k = t >> 5, n = t & 31;
            sm->WT[n * H_ + (((k >> 3) ^ (n & 7)) << 3) + (k & 7)] =
                f2bf(Wg[(size_t)k * H_ + s * 32 + n]);
        }
        __syncthreads();
        if (s == 0) {
            #pragma unroll
            for (int kc = 0; kc < 4; ++kc)
                a[kc] = *(const short8*)&X[fragoff(mrow, kc * 4 + quad)];
        }
        #pragma unroll
        for (int kc = 0; kc < 4; ++kc) {
            short8 bf = *(const short8*)&sm->WT[fragoff(nl, kc * 4 + quad)];
            acc2[s] = __builtin_amdgcn_mfma_f32_16x16x32_bf16(a[kc], bf, acc2[s], 0, 0, 0);
        }
    }
}

extern "C" __global__ __launch_bounds__(NT, 4)
void md17_fused_kernel(
    const float* __restrict__ positions, const int* __restrict__ atomic_numbers,
    const float* __restrict__ atom_embed, const float* __restrict__ pos_W,
    const float* __restrict__ pos_b,
    const float* __restrict__ msg_W, const float* __restrict__ msg_b,
    const float* __restrict__ upd_W, const float* __restrict__ upd_b,
    const float* __restrict__ gself_W, const float* __restrict__ gmean_W,
    const float* __restrict__ g_b,
    const float* __restrict__ fus_W, const float* __restrict__ fus_b,
    const float* __restrict__ ln_g, const float* __restrict__ ln_b,
    const float* __restrict__ cb_W1, const float* __restrict__ cb_b1,
    const float* __restrict__ cb_W2, const float* __restrict__ cb_b2,
    const float* __restrict__ fo_W1, const float* __restrict__ fo_b1,
    const float* __restrict__ fo_W2, const float* __restrict__ fo_b2,
    char* __restrict__ ws, float* __restrict__ out)
{
    __shared__ Smem sm;
    const int b = blockIdx.x;
    const int tid = threadIdx.x;

    char* wsb = ws + (size_t)b * WS_PER_BLOCK;
    float* hws = (float*)wsb;                    // f32 residual stream [64][128]
    uint_t* rbw = (uint_t*)(wsb + 32768);        // packed u8 rbf [64][16][5 words]

    // ---- positions -> LDS ----
    for (int t = tid; t < N_ * 3; t += NT) sm.spos[t] = positions[b * N_ * 3 + t];
    __syncthreads();

    // ---- kNN (validated round-3 logic) + env + u8-packed rbf to ws ----
    if (tid < N_) {
        int n = tid;
        float px = sm.spos[n * 3 + 0], py = sm.spos[n * 3 + 1], pz = sm.spos[n * 3 + 2];
        unsigned long long picked = 1ull << n;
        for (int k = 0; k < K_; ++k) {
            float best = 3e38f; int bi = 0;
            for (int m = 0; m < N_; ++m) {
                if ((picked >> m) & 1ull) continue;
                float dx = __fsub_rn(px, sm.spos[m * 3 + 0]);
                float dy = __fsub_rn(py, sm.spos[m * 3 + 1]);
                float dz = __fsub_rn(pz, sm.spos[m * 3 + 2]);
                float v = __fadd_rn(__fadd_rn(__fmul_rn(dx, dx), __fmul_rn(dy, dy)), __fmul_rn(dz, dz));
                if (v < best) { best = v; bi = m; }
            }
            picked |= 1ull << bi;
            sm.idx[n * K_ + k] = (ushort_t)bi;
            float dd = sqrtf(fmaxf(best, 1e-12f));
            float e = 0.0f;
            if (dd < 5.0f) e = 0.5f * (cosf(3.14159265358979323846f * dd * 0.2f) + 1.0f);
            sm.env[n * K_ + k] = e;
            uint_t pk[5] = {0, 0, 0, 0, 0};
            #pragma unroll
            for (int r = 0; r < R_; ++r) {
                float cc = (float)((double)r * (5.0 / 19.0));
                float t2 = dd - cc;
                uint_t q = (uint_t)(expf(-10.0f * t2 * t2) * 255.0f + 0.5f);
                pk[r >> 2] |= q << ((r & 3) * 8);
            }
            #pragma unroll
            for (int w = 0; w < 5; ++w) rbw[(n * K_ + k) * 5 + w] = pk[w];
        }
    }
    __syncthreads();

    // ---- embeddings -> hws (f32) + Ha (bf16 swizzled) ----
    for (int t = tid; t < N_ * H_; t += NT) {
        int n = t >> 7, f = t & 127;
        float v;
        if (f < 32) {
            v = atom_embed[atomic_numbers[b * N_ + n] * 32 + f];
        } else {
            int j = f - 32;
            v = pos_b[j];
            #pragma unroll
            for (int c = 0; c < 3; ++c)
                v = fmaf(sm.spos[n * 3 + c], pos_W[c * 96 + j], v);
        }
        hws[t] = v;
        sm.Ha[sidx(n, f)] = f2bf(v);
    }

    for (int l = 0; l < L_; ++l) {
        const float* mW  = msg_W + l * 276 * H_;
        const float* mb  = msg_b + l * H_;
        const float* uW  = upd_W + l * H_ * H_;
        const float* ub  = upd_b + l * H_;
        const float* gsW = gself_W + l * H_ * H_;
        const float* gmW = gmean_W + l * H_ * H_;
        const float* gb  = g_b + l * H_;
        const float* fW  = fus_W + l * 2 * H_ * H_;
        const float* fb  = fus_b + l * H_;
        const float* lg  = ln_g + l * H_;
        const float* lb  = ln_b + l * H_;
        const float* c1W = cb_W1 + l * H_ * 4 * H_;
        const float* c1b = cb_b1 + l * 4 * H_;
        const float* c2W = cb_W2 + l * 4 * H_ * H_;
        const float* c2b = cb_b2 + l * H_;

        __syncthreads();   // layer top: prev epilogue / setup writes visible
        if (tid < H_) {
            float s = 0.f;
            for (int n = 0; n < N_; ++n) s += hws[n * H_ + tid];
            sm.hmean[tid] = s * (1.0f / 64.0f);
        }
        __syncthreads();
        if (tid < H_) {
            float s = gb[tid];
            for (int c = 0; c < H_; ++c) s = fmaf(sm.hmean[c], gmW[c * H_ + tid], s);
            sm.gvec[tid] = s;
        }

        // Ai = Ha@Wi + mb -> T1 ; Gm = Ha@Wj -> T2
        do_gemm<0, false>(&sm, sm.Ha, nullptr, mW, nullptr, H_, mb, nullptr, sm.T1, tid);
        do_gemm<1, false>(&sm, sm.Ha, nullptr, mW + 128 * H_, nullptr, H_, nullptr, nullptr, sm.T2, tid);
        __syncthreads();

        // msum (VALU): T1[n][f] = sum_k env*silu(Ai + Gm[idx] + rbf@Wr), in place
        {
            const float* rW = mW + 256 * H_;
            for (int t = tid; t < N_ * 32; t += NT) {
                int n = t >> 5, f0 = (t & 31) << 2;
                f32x4 wr[R_];
                #pragma unroll
                for (int r = 0; r < R_; ++r) {
                    float4 w4 = *reinterpret_cast<const float4*>(rW + r * H_ + f0);
                    wr[r].x = w4.x * (1.0f / 255.0f); wr[r].y = w4.y * (1.0f / 255.0f);
                    wr[r].z = w4.z * (1.0f / 255.0f); wr[r].w = w4.w * (1.0f / 255.0f);
                }
                int ebase = sidx(n, f0);
                uint2 aiu = *reinterpret_cast<const uint2*>(&sm.T1[ebase]);
                float ai0 = lowbf(aiu.x), ai1 = highbf(aiu.x), ai2 = lowbf(aiu.y), ai3 = highbf(aiu.y);
                float s0 = 0.f, s1 = 0.f, s2 = 0.f, s3 = 0.f;
                for (int k = 0; k < K_; ++k) {
                    int j = sm.idx[n * K_ + k];
                    float e = sm.env[n * K_ + k];
                    const uint_t* rb = rbw + (n * K_ + k) * 5;
                    uint_t w0 = rb[0], w1 = rb[1], w2 = rb[2], w3 = rb[3], w4 = rb[4];
                    float r0 = 0.f, r1 = 0.f, r2 = 0.f, r3 = 0.f;
                    uint_t words[5] = {w0, w1, w2, w3, w4};
                    #pragma unroll
                    for (int r = 0; r < R_; ++r) {
                        float rv = (float)((words[r >> 2] >> ((r & 3) * 8)) & 255u);
                        r0 = fmaf(rv, wr[r].x, r0);
                        r1 = fmaf(rv, wr[r].y, r1);
                        r2 = fmaf(rv, wr[r].z, r2);
                        r3 = fmaf(rv, wr[r].w, r3);
                    }
                    uint2 gmu = *reinterpret_cast<const uint2*>(&sm.T2[sidx(j, f0)]);
                    float p0 = ai0 + lowbf(gmu.x) + r0;
                    float p1 = ai1 + highbf(gmu.x) + r1;
                    float p2 = ai2 + lowbf(gmu.y) + r2;
                    float p3 = ai3 + highbf(gmu.y) + r3;
                    s0 = fmaf(siluf(p0), e, s0);
                    s1 = fmaf(siluf(p1), e, s1);
                    s2 = fmaf(siluf(p2), e, s2);
                    s3 = fmaf(siluf(p3), e, s3);
                }
                uint2 o; o.x = pack2(s0, s1); o.y = pack2(s2, s3);
                *reinterpret_cast<uint2*>(&sm.T1[ebase]) = o;
            }
        }
        __syncthreads();

        // local = hws + silu(T1@uW + ub) -> T2
        do_gemm<3, false>(&sm, sm.T1, nullptr, uW, nullptr, H_, ub, hws, sm.T2, tid);
        // glob = silu(Ha@gsW + gvec) -> T1
        do_gemm<2, false>(&sm, sm.Ha, nullptr, gsW, nullptr, H_, sm.gvec, nullptr, sm.T1, tid);
        // fused = silu([T2|T1]@fW + fb) -> Ha (bf16) + hws (f32)
        do_gemm<4, true>(&sm, sm.T2, sm.T1, fW, fW + 128 * H_, H_, fb, hws, sm.Ha, tid);
        __syncthreads();

        // LN(fused from hws f32) -> T2 (bf16)
        {
            int wv = tid >> 6, lane = tid & 63;
            for (int n = wv; n < N_; n += 8) {
                float x0 = hws[n * H_ + lane];
                float x1 = hws[n * H_ + 64 + lane];
                float s = x0 + x1, ss = x0 * x0 + x1 * x1;
                #pragma unroll
                for (int o = 32; o > 0; o >>= 1) {
                    s += __shfl_xor(s, o);
                    ss += __shfl_xor(ss, o);
                }
                float mu = s * (1.0f / 128.0f);
                float var = ss * (1.0f / 128.0f) - mu * mu;
                float rs = rsqrtf(var + 1e-5f);
                sm.T2[sidx(n, lane)]      = f2bf((x0 - mu) * rs * lg[lane] + lb[lane]);
                sm.T2[sidx(n, 64 + lane)] = f2bf((x1 - mu) * rs * lg[64 + lane] + lb[64 + lane]);
            }
        }

        // Clifford MLP: 4 K-chunks, persistent accumulators for cb_W2
        {
            f32x4 acc2[4];
            #pragma unroll
            for (int s = 0; s < 4; ++s) acc2[s] = (f32x4){0.f, 0.f, 0.f, 0.f};
            for (int j = 0; j < 4; ++j) {
                do_gemm<2, false>(&sm, sm.T2, nullptr, c1W + j * H_, nullptr, 4 * H_,
                                  c1b + j * H_, nullptr, sm.T1, tid);
                gemm_acc(&sm, sm.T1, c2W + j * H_ * H_, acc2, tid);
            }
            // epilogue: h_next = fused(hws) + mlp + c2b  -> hws (f32) + Ha (bf16)
            const int wave = tid >> 6, lane = tid & 63;
            const int quad = lane >> 4, l15 = lane & 15;
            const int Mt = wave >> 1;
            const int nl = (wave & 1) * 16 + l15;
            #pragma unroll
            for (int s = 0; s < 4; ++s) {
                #pragma unroll
                for (int r = 0; r < 4; ++r) {
                    int row = Mt * 16 + quad * 4 + r;
                    int col = s * 32 + nl;
                    float v = hws[row * H_ + col] + acc2[s][r] + c2b[col];
                    hws[row * H_ + col] = v;
                    sm.Ha[sidx(row, col)] = f2bf(v);
                }
            }
        }
    }

    // ---- head: T1 = silu(Ha@foW1 + fob1); out = T1@foW2 + fob2 ----
    __syncthreads();
    do_gemm<2, false>(&sm, sm.Ha, nullptr, fo_W1, nullptr, H_, fo_b1, nullptr, sm.T1, tid);
    __syncthreads();
    if (tid < N_ * 3) {
        int n = tid / 3, j = tid - n * 3;
        float s = fo_b2[j];
        for (int c = 0; c < H_; ++c)
            s = fmaf(bf2f(sm.T1[sidx(n, c)]), fo_W2[c * 3 + j], s);
        out[b * N_ * 3 + tid] = s;
    }
}

extern "C" void kernel_launch(void* const* d_in, const int* in_sizes, int n_in,
                              void* d_out, int out_size, void* d_ws, size_t ws_size,
                              hipStream_t stream) {
    (void)in_sizes; (void)n_in; (void)out_size; (void)ws_size;
    md17_fused_kernel<<<B_, NT, 0, stream>>>(
        (const float*)d_in[0], (const int*)d_in[1],
        (const float*)d_in[2], (const float*)d_in[3], (const float*)d_in[4],
        (const float*)d_in[5], (const float*)d_in[6],
        (const float*)d_in[7], (const float*)d_in[8],
        (const float*)d_in[9], (const float*)d_in[10], (const float*)d_in[11],
        (const float*)d_in[12], (const float*)d_in[13],
        (const float*)d_in[14], (const float*)d_in[15],
        (const float*)d_in[16], (const float*)d_in[17],
        (const float*)d_in[18], (const float*)d_in[19],
        (const float*)d_in[20], (const float*)d_in[21],
        (const float*)d_in[22], (const float*)d_in[23],
        (char*)d_ws, (float*)d_out);
}

// Round 5
// 1762.242 us; speedup vs baseline: 4.0346x; 1.9075x over previous
//
#include <hip/hip_runtime.h>

typedef unsigned short ushort_t;
typedef unsigned int uint_t;
typedef __attribute__((ext_vector_type(8))) short short8;
typedef __attribute__((ext_vector_type(4))) float f32x4;

#define B_ 1024
#define N_ 64
#define H_ 128
#define L_ 4
#define K_ 16
#define R_ 20
#define NT 512

// ws layout: [0, 2MB) bf16 weight images; per-block: hws 32KB + rbw 20.5KB
#define WS_WEIGHTS (2u * 1024u * 1024u)
#define WS_BLK_STRIDE 53248u
// per-layer image element offsets (bf16 elems)
#define IMG_L 229376
#define IMG_WI 0
#define IMG_WJ 16384
#define IMG_UW 32768
#define IMG_GS 49152
#define IMG_FT 65536
#define IMG_FB 81920
#define IMG_C1 98304
#define IMG_C2 163840
#define IMG_FO 917504   // = 4*IMG_L
#define N_STAGES 228    // 4*56 + 4

__device__ __forceinline__ ushort_t f2bf(float f) {
    uint_t u = __float_as_uint(f);
    uint_t r = (u + 0x7fffu + ((u >> 16) & 1u)) >> 16;
    return (ushort_t)r;
}
__device__ __forceinline__ float bf2f(ushort_t u) {
    union { uint_t i; float f; } v; v.i = ((uint_t)u) << 16; return v.f;
}
__device__ __forceinline__ float lowbf(uint_t p) {
    union { uint_t i; float f; } v; v.i = p << 16; return v.f;
}
__device__ __forceinline__ float highbf(uint_t p) {
    union { uint_t i; float f; } v; v.i = p & 0xffff0000u; return v.f;
}
__device__ __forceinline__ uint_t pack2(float lo, float hi) {
    return (uint_t)f2bf(lo) | ((uint_t)f2bf(hi) << 16);
}
__device__ __forceinline__ float siluf(float x) { return x / (1.0f + __expf(-x)); }

// 16B async global->LDS (m97-verified width)
__device__ __forceinline__ void ld16_lds(const ushort_t* g, ushort_t* l) {
    __builtin_amdgcn_global_load_lds(
        (const __attribute__((address_space(1))) uint_t*)(const void*)g,
        (__attribute__((address_space(3))) uint_t*)(void*)l, 16, 0, 0);
}

// swizzled element index: 16B-chunk c of row m stored at chunk c ^ (m&7)
__device__ __forceinline__ int sidx(int m, int k) {
    return m * H_ + (((k >> 3) ^ (m & 7)) << 3) + (k & 7);
}
__device__ __forceinline__ int fragoff(int m, int ch) {
    return m * H_ + ((ch ^ (m & 7)) << 3);
}

// ================= preamble: f32 weights -> pre-swizzled bf16 stage images ==
extern "C" __global__ __launch_bounds__(256)
void convert_weights(const float* __restrict__ msg_W, const float* __restrict__ upd_W,
                     const float* __restrict__ gself_W, const float* __restrict__ fus_W,
                     const float* __restrict__ cb_W1, const float* __restrict__ cb_W2,
                     const float* __restrict__ fo_W1, ushort_t* __restrict__ wimg)
{
    const int g = blockIdx.x;        // stage id
    const float* W; int ld, k0, c0;
    if (g >= 224) { W = fo_W1; ld = 128; k0 = 0; c0 = (g - 224) * 32; }
    else {
        int l = g / 56, r = g - l * 56;
        if      (r < 4)  { W = msg_W + l * 35328; ld = 128; k0 = 0;   c0 = r * 32; }
        else if (r < 8)  { W = msg_W + l * 35328; ld = 128; k0 = 128; c0 = (r - 4) * 32; }
        else if (r < 12) { W = upd_W + l * 16384; ld = 128; k0 = 0;   c0 = (r - 8) * 32; }
        else if (r < 16) { W = gself_W + l * 16384; ld = 128; k0 = 0; c0 = (r - 12) * 32; }
        else if (r < 20) { W = fus_W + l * 32768; ld = 128; k0 = 0;   c0 = (r - 16) * 32; }
        else if (r < 24) { W = fus_W + l * 32768; ld = 128; k0 = 128; c0 = (r - 20) * 32; }
        else if (r < 40) { W = cb_W1 + l * 65536; ld = 512; k0 = 0;   c0 = (r - 24) * 32; }
        else { int j = (r - 40) >> 2; W = cb_W2 + l * 65536; ld = 128; k0 = j * 128; c0 = ((r - 40) & 3) * 32; }
    }
    ushort_t* dst = wimg + g * 4096;
    for (int e = 0; e < 16; ++e) {
        int q = threadIdx.x * 16 + e;
        int n = q >> 7, off = q & 127;
        int k = ((((off >> 3) ^ (n & 7)) << 3) | (off & 7));
        dst[q] = f2bf(W[(size_t)(k0 + k) * ld + c0 + n]);
    }
}

// ================= main fused kernel =======================================
// Static LDS: 65280 B -> 2 blocks/CU.
struct __align__(16) Smem {
    ushort_t Ha[N_ * H_];   // 16384B  h (bf16, swizzled)
    ushort_t T1[N_ * H_];   // 16384B
    ushort_t T2[N_ * H_];   // 16384B
    ushort_t WT[32 * H_];   //  8192B  staged weight image (one 32-col stage)
    float spos[N_ * 3];
    float env[N_ * K_];
    float hmean[H_];
    float gvec[H_];
    ushort_t idx[N_ * K_];
};

// EPI: 0=+bias | 1=raw | 2=silu(+bias) | 3=hws+silu(+bias) | 4=silu(+bias)&write hws
template<int EPI, bool DUAL>
__device__ __forceinline__ void do_gemm(
    Smem* sm, const ushort_t* X, const ushort_t* X2,
    const ushort_t* img, const ushort_t* img2,
    const float* bias, float* hws, ushort_t* dst, int tid)
{
    const int wave = tid >> 6, lane = tid & 63;
    const int quad = lane >> 4, l15 = lane & 15;
    const int Mt = wave >> 1;
    const int mrow = Mt * 16 + l15;
    const int nl = (wave & 1) * 16 + l15;
    short8 a[4], a2[4];
    for (int s = 0; s < 4; ++s) {
        __syncthreads();                       // WT free; inputs stable
        ld16_lds(img + s * 4096 + tid * 8, &sm->WT[tid * 8]);
        __syncthreads();
        if (s == 0) {
            #pragma unroll
            for (int kc = 0; kc < 4; ++kc) {
                a[kc] = *(const short8*)&X[fragoff(mrow, kc * 4 + quad)];
                if (DUAL) a2[kc] = *(const short8*)&X2[fragoff(mrow, kc * 4 + quad)];
            }
        }
        f32x4 acc = {0.f, 0.f, 0.f, 0.f};
        #pragma unroll
        for (int kc = 0; kc < 4; ++kc) {
            short8 bf = *(const short8*)&sm->WT[fragoff(nl, kc * 4 + quad)];
            acc = __builtin_amdgcn_mfma_f32_16x16x32_bf16(a[kc], bf, acc, 0, 0, 0);
        }
        if (DUAL) {
            __syncthreads();
            ld16_lds(img2 + s * 4096 + tid * 8, &sm->WT[tid * 8]);
            __syncthreads();
            #pragma unroll
            for (int kc = 0; kc < 4; ++kc) {
                short8 bf = *(const short8*)&sm->WT[fragoff(nl, kc * 4 + quad)];
                acc = __builtin_amdgcn_mfma_f32_16x16x32_bf16(a2[kc], bf, acc, 0, 0, 0);
            }
        }
        #pragma unroll
        for (int r = 0; r < 4; ++r) {
            int row = Mt * 16 + quad * 4 + r;
            int col = s * 32 + nl;
            float v = acc[r];
            if (EPI == 0) v += bias[col];
            if (EPI == 2) v = siluf(v + bias[col]);
            if (EPI == 3) v = hws[row * H_ + col] + siluf(v + bias[col]);
            if (EPI == 4) { v = siluf(v + bias[col]); hws[row * H_ + col] = v; }
            dst[sidx(row, col)] = f2bf(v);
        }
    }
}

// persistent-accumulator GEMM (cb_W2 chunks)
__device__ __forceinline__ void gemm_acc(
    Smem* sm, const ushort_t* X, const ushort_t* img, f32x4 acc2[4], int tid)
{
    const int wave = tid >> 6, lane = tid & 63;
    const int quad = lane >> 4, l15 = lane & 15;
    const int Mt = wave >> 1;
    const int mrow = Mt * 16 + l15;
    const int nl = (wave & 1) * 16 + l15;
    short8 a[4];
    for (int s = 0; s < 4; ++s) {
        __syncthreads();
        ld16_lds(img + s * 4096 + tid * 8, &sm->WT[tid * 8]);
        __syncthreads();
        if (s == 0) {
            #pragma unroll
            for (int kc = 0; kc < 4; ++kc)
                a[kc] = *(const short8*)&X[fragoff(mrow, kc * 4 + quad)];
        }
        #pragma unroll
        for (int kc = 0; kc < 4; ++kc) {
            short8 bf = *(const short8*)&sm->WT[fragoff(nl, kc * 4 + quad)];
            acc2[s] = __builtin_amdgcn_mfma_f32_16x16x32_bf16(a[kc], bf, acc2[s], 0, 0, 0);
        }
    }
}

extern "C" __global__ __launch_bounds__(NT, 4)
void md17_fused_kernel(
    const float* __restrict__ positions, const int* __restrict__ atomic_numbers,
    const float* __restrict__ atom_embed, const float* __restrict__ pos_W,
    const float* __restrict__ pos_b,
    const float* __restrict__ msg_W, const float* __restrict__ msg_b,
    const float* __restrict__ upd_b,
    const float* __restrict__ gmean_W, const float* __restrict__ g_b,
    const float* __restrict__ fus_b,
    const float* __restrict__ ln_g, const float* __restrict__ ln_b,
    const float* __restrict__ cb_b1, const float* __restrict__ cb_b2,
    const float* __restrict__ fo_b1,
    const float* __restrict__ fo_W2, const float* __restrict__ fo_b2,
    char* __restrict__ ws, float* __restrict__ out)
{
    __shared__ Smem sm;
    const int b = blockIdx.x;
    const int tid = threadIdx.x;

    const ushort_t* wimg = (const ushort_t*)ws;
    char* wsb = ws + WS_WEIGHTS + (size_t)b * WS_BLK_STRIDE;
    float* hws = (float*)wsb;               // f32 residual stream [64][128]
    uint_t* rbw = (uint_t*)(wsb + 32768);   // packed u8 rbf [64][16][5]

    for (int t = tid; t < N_ * 3; t += NT) sm.spos[t] = positions[b * N_ * 3 + t];
    __syncthreads();

    // ---- kNN + env + u8 rbf (round-3/4 validated logic) ----
    if (tid < N_) {
        int n = tid;
        float px = sm.spos[n * 3 + 0], py = sm.spos[n * 3 + 1], pz = sm.spos[n * 3 + 2];
        unsigned long long picked = 1ull << n;
        for (int k = 0; k < K_; ++k) {
            float best = 3e38f; int bi = 0;
            for (int m = 0; m < N_; ++m) {
                if ((picked >> m) & 1ull) continue;
                float dx = __fsub_rn(px, sm.spos[m * 3 + 0]);
                float dy = __fsub_rn(py, sm.spos[m * 3 + 1]);
                float dz = __fsub_rn(pz, sm.spos[m * 3 + 2]);
                float v = __fadd_rn(__fadd_rn(__fmul_rn(dx, dx), __fmul_rn(dy, dy)), __fmul_rn(dz, dz));
                if (v < best) { best = v; bi = m; }
            }
            picked |= 1ull << bi;
            sm.idx[n * K_ + k] = (ushort_t)bi;
            float dd = sqrtf(fmaxf(best, 1e-12f));
            float e = 0.0f;
            if (dd < 5.0f) e = 0.5f * (cosf(3.14159265358979323846f * dd * 0.2f) + 1.0f);
            sm.env[n * K_ + k] = e;
            uint_t pk[5] = {0, 0, 0, 0, 0};
            #pragma unroll
            for (int r = 0; r < R_; ++r) {
                float cc = (float)((double)r * (5.0 / 19.0));
                float t2 = dd - cc;
                uint_t q = (uint_t)(expf(-10.0f * t2 * t2) * 255.0f + 0.5f);
                pk[r >> 2] |= q << ((r & 3) * 8);
            }
            #pragma unroll
            for (int w = 0; w < 5; ++w) rbw[(n * K_ + k) * 5 + w] = pk[w];
        }
    }
    __syncthreads();

    // ---- embeddings -> hws (f32) + Ha (bf16 swizzled) ----
    for (int t = tid; t < N_ * H_; t += NT) {
        int n = t >> 7, f = t & 127;
        float v;
        if (f < 32) {
            v = atom_embed[atomic_numbers[b * N_ + n] * 32 + f];
        } else {
            int j = f - 32;
            v = pos_b[j];
            #pragma unroll
            for (int c = 0; c < 3; ++c)
                v = fmaf(sm.spos[n * 3 + c], pos_W[c * 96 + j], v);
        }
        hws[t] = v;
        sm.Ha[sidx(n, f)] = f2bf(v);
    }

    for (int l = 0; l < L_; ++l) {
        const ushort_t* wl = wimg + l * IMG_L;
        const float* mb  = msg_b + l * H_;
        const float* ub  = upd_b + l * H_;
        const float* gmW = gmean_W + l * H_ * H_;
        const float* gb  = g_b + l * H_;
        const float* fb  = fus_b + l * H_;
        const float* lg  = ln_g + l * H_;
        const float* lb  = ln_b + l * H_;
        const float* c1b = cb_b1 + l * 4 * H_;
        const float* c2b = cb_b2 + l * H_;

        __syncthreads();
        if (tid < H_) {
            float s = 0.f;
            for (int n = 0; n < N_; ++n) s += hws[n * H_ + tid];
            sm.hmean[tid] = s * (1.0f / 64.0f);
        }
        __syncthreads();
        if (tid < H_) {
            float s = gb[tid];
            for (int c = 0; c < H_; ++c) s = fmaf(sm.hmean[c], gmW[c * H_ + tid], s);
            sm.gvec[tid] = s;
        }

        // Ai = Ha@Wi + mb -> T1 ; Gm = Ha@Wj -> T2
        do_gemm<0, false>(&sm, sm.Ha, nullptr, wl + IMG_WI, nullptr, mb, nullptr, sm.T1, tid);
        do_gemm<1, false>(&sm, sm.Ha, nullptr, wl + IMG_WJ, nullptr, nullptr, nullptr, sm.T2, tid);
        __syncthreads();

        // msum (VALU): T1[n][f] = sum_k env*silu(Ai + Gm[idx] + rbf@Wr), in place
        {
            const float* rW = msg_W + l * 35328 + 256 * H_;
            for (int t = tid; t < N_ * 32; t += NT) {
                int n = t >> 5, f0 = (t & 31) << 2;
                f32x4 wr[R_];
                #pragma unroll
                for (int r = 0; r < R_; ++r) {
                    float4 w4 = *reinterpret_cast<const float4*>(rW + r * H_ + f0);
                    wr[r].x = w4.x * (1.0f / 255.0f); wr[r].y = w4.y * (1.0f / 255.0f);
                    wr[r].z = w4.z * (1.0f / 255.0f); wr[r].w = w4.w * (1.0f / 255.0f);
                }
                int ebase = sidx(n, f0);
                uint2 aiu = *reinterpret_cast<const uint2*>(&sm.T1[ebase]);
                float ai0 = lowbf(aiu.x), ai1 = highbf(aiu.x), ai2 = lowbf(aiu.y), ai3 = highbf(aiu.y);
                float s0 = 0.f, s1 = 0.f, s2 = 0.f, s3 = 0.f;
                for (int k = 0; k < K_; ++k) {
                    int j = sm.idx[n * K_ + k];
                    float e = sm.env[n * K_ + k];
                    const uint_t* rb = rbw + (n * K_ + k) * 5;
                    uint_t words[5] = {rb[0], rb[1], rb[2], rb[3], rb[4]};
                    float r0 = 0.f, r1 = 0.f, r2 = 0.f, r3 = 0.f;
                    #pragma unroll
                    for (int r = 0; r < R_; ++r) {
                        float rv = (float)((words[r >> 2] >> ((r & 3) * 8)) & 255u);
                        r0 = fmaf(rv, wr[r].x, r0);
                        r1 = fmaf(rv, wr[r].y, r1);
                        r2 = fmaf(rv, wr[r].z, r2);
                        r3 = fmaf(rv, wr[r].w, r3);
                    }
                    uint2 gmu = *reinterpret_cast<const uint2*>(&sm.T2[sidx(j, f0)]);
                    float p0 = ai0 + lowbf(gmu.x) + r0;
                    float p1 = ai1 + highbf(gmu.x) + r1;
                    float p2 = ai2 + lowbf(gmu.y) + r2;
                    float p3 = ai3 + highbf(gmu.y) + r3;
                    s0 = fmaf(siluf(p0), e, s0);
                    s1 = fmaf(siluf(p1), e, s1);
                    s2 = fmaf(siluf(p2), e, s2);
                    s3 = fmaf(siluf(p3), e, s3);
                }
                uint2 o; o.x = pack2(s0, s1); o.y = pack2(s2, s3);
                *reinterpret_cast<uint2*>(&sm.T1[ebase]) = o;
            }
        }
        __syncthreads();

        // local = hws + silu(T1@uW + ub) -> T2
        do_gemm<3, false>(&sm, sm.T1, nullptr, wl + IMG_UW, nullptr, ub, hws, sm.T2, tid);
        // glob = silu(Ha@gsW + gvec) -> T1
        do_gemm<2, false>(&sm, sm.Ha, nullptr, wl + IMG_GS, nullptr, sm.gvec, nullptr, sm.T1, tid);
        // fused = silu([T2|T1]@fW + fb) -> Ha (bf16) + hws (f32)
        do_gemm<4, true>(&sm, sm.T2, sm.T1, wl + IMG_FT, wl + IMG_FB, fb, hws, sm.Ha, tid);
        __syncthreads();

        // LN(fused, f32 from hws) -> T2 (bf16)
        {
            int wv = tid >> 6, lane = tid & 63;
            for (int n = wv; n < N_; n += 8) {
                float x0 = hws[n * H_ + lane];
                float x1 = hws[n * H_ + 64 + lane];
                float s = x0 + x1, ss = x0 * x0 + x1 * x1;
                #pragma unroll
                for (int o = 32; o > 0; o >>= 1) {
                    s += __shfl_xor(s, o);
                    ss += __shfl_xor(ss, o);
                }
                float mu = s * (1.0f / 128.0f);
                float var = ss * (1.0f / 128.0f) - mu * mu;
                float rs = rsqrtf(var + 1e-5f);
                sm.T2[sidx(n, lane)]      = f2bf((x0 - mu) * rs * lg[lane] + lb[lane]);
                sm.T2[sidx(n, 64 + lane)] = f2bf((x1 - mu) * rs * lg[64 + lane] + lb[64 + lane]);
            }
        }

        // Clifford MLP: 4 K-chunks, persistent accumulators for cb_W2
        {
            f32x4 acc2[4];
            #pragma unroll
            for (int s = 0; s < 4; ++s) acc2[s] = (f32x4){0.f, 0.f, 0.f, 0.f};
            for (int j = 0; j < 4; ++j) {
                do_gemm<2, false>(&sm, sm.T2, nullptr, wl + IMG_C1 + j * 16384, nullptr,
                                  c1b + j * H_, nullptr, sm.T1, tid);
                gemm_acc(&sm, sm.T1, wl + IMG_C2 + j * 16384, acc2, tid);
            }
            const int wave = tid >> 6, lane = tid & 63;
            const int quad = lane >> 4, l15 = lane & 15;
            const int Mt = wave >> 1;
            const int nl = (wave & 1) * 16 + l15;
            #pragma unroll
            for (int s = 0; s < 4; ++s) {
                #pragma unroll
                for (int r = 0; r < 4; ++r) {
                    int row = Mt * 16 + quad * 4 + r;
                    int col = s * 32 + nl;
                    float v = hws[row * H_ + col] + acc2[s][r] + c2b[col];
                    hws[row * H_ + col] = v;
                    sm.Ha[sidx(row, col)] = f2bf(v);
                }
            }
        }
    }

    // ---- head ----
    __syncthreads();
    do_gemm<2, false>(&sm, sm.Ha, nullptr, wimg + IMG_FO, nullptr, fo_b1, nullptr, sm.T1, tid);
    __syncthreads();
    if (tid < N_ * 3) {
        int n = tid / 3, j = tid - n * 3;
        float s = fo_b2[j];
        for (int c = 0; c < H_; ++c)
            s = fmaf(bf2f(sm.T1[sidx(n, c)]), fo_W2[c * 3 + j], s);
        out[b * N_ * 3 + tid] = s;
    }
}

extern "C" void kernel_launch(void* const* d_in, const int* in_sizes, int n_in,
                              void* d_out, int out_size, void* d_ws, size_t ws_size,
                              hipStream_t stream) {
    (void)in_sizes; (void)n_in; (void)out_size; (void)ws_size;
    convert_weights<<<N_STAGES, 256, 0, stream>>>(
        (const float*)d_in[5], (const float*)d_in[7], (const float*)d_in[9],
        (const float*)d_in[12], (const float*)d_in[16], (const float*)d_in[18],
        (const float*)d_in[20], (ushort_t*)d_ws);
    md17_fused_kernel<<<B_, NT, 0, stream>>>(
        (const float*)d_in[0], (const int*)d_in[1],
        (const float*)d_in[2], (const float*)d_in[3], (const float*)d_in[4],
        (const float*)d_in[5], (const float*)d_in[6],
        (const float*)d_in[8],
        (const float*)d_in[10], (const float*)d_in[11],
        (const float*)d_in[13],
        (const float*)d_in[14], (const float*)d_in[15],
        (const float*)d_in[17], (const float*)d_in[19],
        (const float*)d_in[21],
        (const float*)d_in[22], (const float*)d_in[23],
        (char*)d_ws, (float*)d_out);
}

// Round 6
// 1699.172 us; speedup vs baseline: 4.1843x; 1.0371x over previous
//
#include <hip/hip_runtime.h>

typedef unsigned short ushort_t;
typedef unsigned int uint_t;
typedef unsigned long long ull_t;
typedef __attribute__((ext_vector_type(8))) short short8;
typedef __attribute__((ext_vector_type(4))) float f32x4;

#define B_ 1024
#define N_ 64
#define H_ 128
#define NT 512

// bf16 weight-image element offsets
#define IMG_WI 0
#define IMG_WJ 16384
#define IMG_UW 32768
#define IMG_GS 49152
#define IMG_FT 65536
#define IMG_FB 81920
#define IMG_C1 98304
#define IMG_C2 163840
#define IMG_GMT 229376
#define IMG_RW 245760
#define IMG_L 249856
#define IMG_FO 999424
#define WS_WEIGHTS (2u*1024u*1024u)
#define WS_RBF_STRIDE 65536u

__device__ __forceinline__ ushort_t f2bf(float f) {
    uint_t u = __float_as_uint(f);
    return (ushort_t)((u + 0x7fffu + ((u >> 16) & 1u)) >> 16);
}
__device__ __forceinline__ float bf2f(ushort_t u) {
    union { uint_t i; float f; } v; v.i = ((uint_t)u) << 16; return v.f;
}
__device__ __forceinline__ float lowbf(uint_t p) {
    union { uint_t i; float f; } v; v.i = p << 16; return v.f;
}
__device__ __forceinline__ float highbf(uint_t p) {
    union { uint_t i; float f; } v; v.i = p & 0xffff0000u; return v.f;
}
__device__ __forceinline__ uint_t pack2(float lo, float hi) {
    return (uint_t)f2bf(lo) | ((uint_t)f2bf(hi) << 16);
}
__device__ __forceinline__ float siluf(float x) { return x / (1.0f + __expf(-x)); }

// LDS swizzle: 16B-chunk c of row m stored at chunk c ^ (m&7)
__device__ __forceinline__ int sidx(int m, int k) {
    return m * H_ + (((k >> 3) ^ (m & 7)) << 3) + (k & 7);
}
__device__ __forceinline__ int fragoff(int m, int ch) {
    return m * H_ + ((ch ^ (m & 7)) << 3);
}

// ========== preamble: f32 weights -> transposed bf16 images (plain layout) ==
extern "C" __global__ __launch_bounds__(256)
void convert_weights(const float* __restrict__ msg_W, const float* __restrict__ upd_W,
                     const float* __restrict__ gself_W, const float* __restrict__ fus_W,
                     const float* __restrict__ cb_W1, const float* __restrict__ cb_W2,
                     const float* __restrict__ gmean_W, const float* __restrict__ fo_W1,
                     ushort_t* __restrict__ wimg)
{
    const int g = blockIdx.x;
    if (g >= 244) {                      // fo_W1: 4 stages
        int st = g - 244;
        ushort_t* dst = wimg + IMG_FO + st * 4096;
        for (int e = 0; e < 16; ++e) {
            int q = threadIdx.x * 16 + e;
            int n = q >> 7, k = q & 127;
            dst[q] = f2bf(fo_W1[(size_t)k * 128 + st * 32 + n]);
        }
        return;
    }
    const int l = g / 61, r = g - l * 61;
    ushort_t* base = wimg + l * IMG_L;
    if (r == 60) {                       // rW pad image: 4 sub-stages [32f][32k]
        const float* W = msg_W + l * 35328 + 256 * 128;
        ushort_t* dst = base + IMG_RW;
        for (int e = 0; e < 16; ++e) {
            int q = threadIdx.x * 16 + e;
            int sub = q >> 10, n = (q >> 5) & 31, k = q & 31;
            dst[q] = f2bf(k < 20 ? W[(size_t)k * 128 + sub * 32 + n] : 0.0f);
        }
        return;
    }
    const float* W; int ld = 128, k0 = 0, c0, off, st;
    if      (r < 4)  { W = msg_W + l * 35328;            st = r;      off = IMG_WI;  c0 = st * 32; }
    else if (r < 8)  { W = msg_W + l * 35328;  k0 = 128; st = r - 4;  off = IMG_WJ;  c0 = st * 32; }
    else if (r < 12) { W = upd_W + l * 16384;            st = r - 8;  off = IMG_UW;  c0 = st * 32; }
    else if (r < 16) { W = gself_W + l * 16384;          st = r - 12; off = IMG_GS;  c0 = st * 32; }
    else if (r < 20) { W = fus_W + l * 32768;            st = r - 16; off = IMG_FT;  c0 = st * 32; }
    else if (r < 24) { W = fus_W + l * 32768;  k0 = 128; st = r - 20; off = IMG_FB;  c0 = st * 32; }
    else if (r < 40) { W = cb_W1 + l * 65536;  ld = 512; st = r - 24; off = IMG_C1;  c0 = st * 32; }
    else if (r < 56) { int j = (r - 40) >> 2; W = cb_W2 + l * 65536; k0 = j * 128;
                       st = r - 40; off = IMG_C2; c0 = ((r - 40) & 3) * 32; }
    else             { W = gmean_W + l * 16384;          st = r - 56; off = IMG_GMT; c0 = st * 32; }
    ushort_t* dst = base + off + st * 4096;
    for (int e = 0; e < 16; ++e) {
        int q = threadIdx.x * 16 + e;
        int n = q >> 7, k = q & 127;
        dst[q] = f2bf(W[(size_t)(k0 + k) * ld + c0 + n]);
    }
}

// ========== main fused kernel ==============================================
struct __align__(16) Smem {
    ushort_t Ha[N_ * H_];   // 16384B  h bf16 swizzled; aliased as rproj buffer in msum
    ushort_t T1[N_ * H_];   // 16384B
    ushort_t T2[N_ * H_];   // 16384B
    float spos[N_ * 3];     //   768
    float env[N_ * 16];     //  4096  (phase A: d2; phase B+: envelope)
    float hmean[H_];        //   512
    float gvec[H_];         //   512
    ushort_t idx[N_ * 16];  //  2048
    int kcnt[N_];           //   256
    float lnbuf[N_ * 4];    //  1024  [row][half] (sum, ss)
};                          // total 58368 B

// 16-MFMA K=128 GEMM step: B-frags straight from global image
__device__ __forceinline__ void mfma4(const short8 a[4], const ushort_t* __restrict__ img,
                                      int nl, int quad, f32x4 acc[4])
{
    #pragma unroll
    for (int s = 0; s < 4; ++s) {
        f32x4 c = {0.f, 0.f, 0.f, 0.f};
        #pragma unroll
        for (int kc = 0; kc < 4; ++kc) {
            short8 bv = *(const short8*)(img + s * 4096 + nl * 128 + (kc * 4 + quad) * 8);
            c = __builtin_amdgcn_mfma_f32_16x16x32_bf16(a[kc], bv, c, 0, 0, 0);
        }
        acc[s] = c;
    }
}
__device__ __forceinline__ void loadA(const ushort_t* __restrict__ X, int mrow, int quad, short8 a[4]) {
    #pragma unroll
    for (int kc = 0; kc < 4; ++kc) a[kc] = *(const short8*)&X[fragoff(mrow, kc * 4 + quad)];
}

extern "C" __global__ __launch_bounds__(NT, 4)
void md17_fused_kernel(
    const float* __restrict__ positions, const int* __restrict__ atomic_numbers,
    const float* __restrict__ atom_embed, const float* __restrict__ pos_W,
    const float* __restrict__ pos_b,
    const float* __restrict__ msg_b, const float* __restrict__ upd_b,
    const float* __restrict__ g_b, const float* __restrict__ fus_b,
    const float* __restrict__ ln_g, const float* __restrict__ ln_b,
    const float* __restrict__ cb_b1, const float* __restrict__ cb_b2,
    const float* __restrict__ fo_b1,
    const float* __restrict__ fo_W2, const float* __restrict__ fo_b2,
    char* __restrict__ ws, float* __restrict__ out)
{
    __shared__ Smem sm;
    const int b = blockIdx.x;
    const int tid = threadIdx.x;
    const int wave = tid >> 6, lane = tid & 63;
    const int quad = lane >> 4, l15 = lane & 15;
    const int Mt = wave >> 1;
    const int mrow = Mt * 16 + l15;
    const int nl = (wave & 1) * 16 + l15;

    const ushort_t* wimg = (const ushort_t*)ws;
    ushort_t* wsrbf = (ushort_t*)(ws + WS_WEIGHTS + (size_t)b * WS_RBF_STRIDE); // [1024][32] bf16

    for (int t = tid; t < N_ * 3; t += NT) sm.spos[t] = positions[b * N_ * 3 + t];
    __syncthreads();

    // ---- kNN: wave w handles atoms w*8..w*8+7; butterfly-min + ballot ----
    {
        const int m = lane;
        for (int a = 0; a < 8; ++a) {
            int n = wave * 8 + a;
            float dx = __fsub_rn(sm.spos[n * 3 + 0], sm.spos[m * 3 + 0]);
            float dy = __fsub_rn(sm.spos[n * 3 + 1], sm.spos[m * 3 + 1]);
            float dz = __fsub_rn(sm.spos[n * 3 + 2], sm.spos[m * 3 + 2]);
            float d2 = __fadd_rn(__fadd_rn(__fmul_rn(dx, dx), __fmul_rn(dy, dy)), __fmul_rn(dz, dz));
            if (m == n) d2 = 1e30f;
            int cnt = 0;
            for (int k = 0; k < 16; ++k) {
                float dmin = d2;
                #pragma unroll
                for (int o = 1; o < 64; o <<= 1) dmin = fminf(dmin, __shfl_xor(dmin, o));
                ull_t mask = __ballot(d2 == dmin);
                int widx = __ffsll((ull_t)mask) - 1;   // lowest index on ties (= top_k)
                if (lane == widx) d2 = 1e30f;
                if (lane == k) { sm.idx[n * 16 + k] = (ushort_t)widx; sm.env[n * 16 + k] = dmin; }
                if (dmin < 25.0f) ++cnt;               // env>0 prefix (ascending d2)
            }
            if (lane == 0) sm.kcnt[n] = cnt;
        }
    }
    __syncthreads();

    // ---- phase B: envelope + bf16 rbf rows (K=32 zero-padded) -> ws ----
    for (int p = tid; p < 1024; p += NT) {
        float dd = sqrtf(fmaxf(sm.env[p], 1e-12f));
        float e = 0.0f;
        if (dd < 5.0f) e = 0.5f * (cosf(3.14159265358979323846f * dd * 0.2f) + 1.0f);
        sm.env[p] = e;
        ushort_t buf[32];
        #pragma unroll
        for (int r = 0; r < 20; ++r) {
            float cc = (float)((double)r * (5.0 / 19.0));
            float t2 = dd - cc;
            buf[r] = f2bf(expf(-10.0f * t2 * t2));
        }
        #pragma unroll
        for (int r = 20; r < 32; ++r) buf[r] = 0;
        uint4* dst = (uint4*)(wsrbf + p * 32);
        uint4* src = (uint4*)buf;
        #pragma unroll
        for (int w = 0; w < 4; ++w) dst[w] = src[w];
    }

    // ---- embeddings -> hreg (f32 C-layout) + Ha ----
    float hreg[4][4];
    {
        int types[4];
        #pragma unroll
        for (int r = 0; r < 4; ++r) types[r] = atomic_numbers[b * N_ + Mt * 16 + quad * 4 + r];
        #pragma unroll
        for (int s = 0; s < 4; ++s) {
            int col = s * 32 + nl;
            #pragma unroll
            for (int r = 0; r < 4; ++r) {
                int row = Mt * 16 + quad * 4 + r;
                float v;
                if (col < 32) v = atom_embed[types[r] * 32 + col];
                else {
                    int j = col - 32;
                    v = pos_b[j];
                    #pragma unroll
                    for (int c = 0; c < 3; ++c)
                        v = fmaf(sm.spos[row * 3 + c], pos_W[c * 96 + j], v);
                }
                hreg[s][r] = v;
                sm.Ha[sidx(row, col)] = f2bf(v);
            }
        }
    }
    __syncthreads();

    for (int l = 0; l < 4; ++l) {
        const ushort_t* wl = wimg + l * IMG_L;
        const float* mb  = msg_b + l * H_;
        const float* ub  = upd_b + l * H_;
        const float* gb  = g_b + l * H_;
        const float* fb  = fus_b + l * H_;
        const float* lg  = ln_g + l * H_;
        const float* lb  = ln_b + l * H_;
        const float* c1b = cb_b1 + l * 4 * H_;
        const float* c2b = cb_b2 + l * H_;

        // --- hmean (from Ha bf16) + gvec GEMV (gmW^T bf16 image) ---
        if (tid < H_) {
            float s = 0.f;
            for (int n = 0; n < N_; ++n) s += bf2f(sm.Ha[sidx(n, tid)]);
            sm.hmean[tid] = s * (1.0f / 64.0f);
        }
        __syncthreads();
        if (tid < H_) {
            float s = gb[tid];
            const ushort_t* wrow = wl + IMG_GMT + tid * 128;
            for (int c = 0; c < 128; c += 8) {
                short8 w = *(const short8*)(wrow + c);
                #pragma unroll
                for (int i = 0; i < 8; ++i) s = fmaf(sm.hmean[c + i], bf2f((ushort_t)w[i]), s);
            }
            sm.gvec[tid] = s;
        }
        __syncthreads();

        // --- WI -> T1, WJ -> T2, GS -> greg ---
        float greg[4][4];
        {
            short8 a_h[4]; loadA(sm.Ha, mrow, quad, a_h);
            f32x4 acc[4];
            mfma4(a_h, wl + IMG_WI, nl, quad, acc);
            #pragma unroll
            for (int s = 0; s < 4; ++s) {
                int col = s * 32 + nl; float bv = mb[col];
                #pragma unroll
                for (int r = 0; r < 4; ++r)
                    sm.T1[sidx(Mt * 16 + quad * 4 + r, col)] = f2bf(acc[s][r] + bv);
            }
            mfma4(a_h, wl + IMG_WJ, nl, quad, acc);
            #pragma unroll
            for (int s = 0; s < 4; ++s) {
                int col = s * 32 + nl;
                #pragma unroll
                for (int r = 0; r < 4; ++r)
                    sm.T2[sidx(Mt * 16 + quad * 4 + r, col)] = f2bf(acc[s][r]);
            }
            mfma4(a_h, wl + IMG_GS, nl, quad, acc);
            #pragma unroll
            for (int s = 0; s < 4; ++s) {
                float gv = sm.gvec[s * 32 + nl];
                #pragma unroll
                for (int r = 0; r < 4; ++r) greg[s][r] = siluf(acc[s][r] + gv);
            }
        }
        __syncthreads();

        // --- msum: 16 groups of 4 atoms; rproj via MFMA into Ha region ---
        {
            ushort_t* PR = sm.Ha;             // h image dead until final epilogue
            const int nloc = tid >> 7, f0g = (tid >> 2) & 31, ks = tid & 3;
            const int f0 = f0g * 4;
            for (int g = 0; g < 16; ++g) {
                // rproj[64 rows][128] = rbf(K=32) @ WrT
                short8 arb = *(const short8*)(wsrbf + (g * 64 + mrow) * 32 + quad * 8);
                const ushort_t* img = wl + IMG_RW;
                #pragma unroll
                for (int s = 0; s < 4; ++s) {
                    short8 bv = *(const short8*)(img + s * 1024 + nl * 32 + quad * 8);
                    f32x4 c = {0.f, 0.f, 0.f, 0.f};
                    c = __builtin_amdgcn_mfma_f32_16x16x32_bf16(arb, bv, c, 0, 0, 0);
                    int col = s * 32 + nl;
                    #pragma unroll
                    for (int r = 0; r < 4; ++r)
                        PR[sidx(Mt * 16 + quad * 4 + r, col)] = f2bf(c[r]);
                }
                __syncthreads();
                // VALU: 4 atoms x 32 fgroups x 4 ksplits
                int n = g * 4 + nloc;
                int kc_n = sm.kcnt[n];
                uint2 aiu = *(const uint2*)&sm.T1[sidx(n, f0)];
                float ai0 = lowbf(aiu.x), ai1 = highbf(aiu.x), ai2 = lowbf(aiu.y), ai3 = highbf(aiu.y);
                float s0 = 0.f, s1 = 0.f, s2 = 0.f, s3 = 0.f;
                #pragma unroll
                for (int kk = 0; kk < 4; ++kk) {
                    int k = ks * 4 + kk;
                    if (k < kc_n) {
                        int j = sm.idx[n * 16 + k];
                        float e = sm.env[n * 16 + k];
                        uint2 pru = *(const uint2*)&PR[sidx(nloc * 16 + k, f0)];
                        uint2 gmu = *(const uint2*)&sm.T2[sidx(j, f0)];
                        float p0 = ai0 + lowbf(gmu.x) + lowbf(pru.x);
                        float p1 = ai1 + highbf(gmu.x) + highbf(pru.x);
                        float p2 = ai2 + lowbf(gmu.y) + lowbf(pru.y);
                        float p3 = ai3 + highbf(gmu.y) + highbf(pru.y);
                        s0 = fmaf(siluf(p0), e, s0);
                        s1 = fmaf(siluf(p1), e, s1);
                        s2 = fmaf(siluf(p2), e, s2);
                        s3 = fmaf(siluf(p3), e, s3);
                    }
                }
                #pragma unroll
                for (int o = 1; o < 4; o <<= 1) {
                    s0 += __shfl_xor(s0, o); s1 += __shfl_xor(s1, o);
                    s2 += __shfl_xor(s2, o); s3 += __shfl_xor(s3, o);
                }
                if (ks == 0) {
                    uint2 ov; ov.x = pack2(s0, s1); ov.y = pack2(s2, s3);
                    *(uint2*)&sm.T1[sidx(n, f0)] = ov;
                }
                __syncthreads();
            }
        }

        // --- UW: local = hreg + silu(T1@uW + ub) -> T2 ; dump greg -> T1 ---
        {
            short8 a_m[4]; loadA(sm.T1, mrow, quad, a_m);
            __syncthreads();                 // all a_m loaded before T1 overwrite
            f32x4 acc[4];
            mfma4(a_m, wl + IMG_UW, nl, quad, acc);
            #pragma unroll
            for (int s = 0; s < 4; ++s) {
                int col = s * 32 + nl; float bv = ub[col];
                #pragma unroll
                for (int r = 0; r < 4; ++r)
                    sm.T2[sidx(Mt * 16 + quad * 4 + r, col)] = f2bf(hreg[s][r] + siluf(acc[s][r] + bv));
            }
            #pragma unroll
            for (int s = 0; s < 4; ++s) {
                int col = s * 32 + nl;
                #pragma unroll
                for (int r = 0; r < 4; ++r)
                    sm.T1[sidx(Mt * 16 + quad * 4 + r, col)] = f2bf(greg[s][r]);
            }
        }
        __syncthreads();

        // --- fused = silu([local|glob] @ [FT;FB] + fb) -> hreg ---
        {
            short8 a_loc[4], a_gl[4];
            loadA(sm.T2, mrow, quad, a_loc);
            loadA(sm.T1, mrow, quad, a_gl);
            #pragma unroll
            for (int s = 0; s < 4; ++s) {
                f32x4 c = {0.f, 0.f, 0.f, 0.f};
                #pragma unroll
                for (int kc = 0; kc < 4; ++kc) {
                    short8 bv = *(const short8*)(wl + IMG_FT + s * 4096 + nl * 128 + (kc * 4 + quad) * 8);
                    c = __builtin_amdgcn_mfma_f32_16x16x32_bf16(a_loc[kc], bv, c, 0, 0, 0);
                }
                #pragma unroll
                for (int kc = 0; kc < 4; ++kc) {
                    short8 bv = *(const short8*)(wl + IMG_FB + s * 4096 + nl * 128 + (kc * 4 + quad) * 8);
                    c = __builtin_amdgcn_mfma_f32_16x16x32_bf16(a_gl[kc], bv, c, 0, 0, 0);
                }
                int col = s * 32 + nl; float bv = fb[col];
                #pragma unroll
                for (int r = 0; r < 4; ++r) hreg[s][r] = siluf(c[r] + bv);
            }
        }
        __syncthreads();

        // --- LN(hreg) -> T2 ---
        {
            float2* lnb = (float2*)sm.lnbuf;
            #pragma unroll
            for (int r = 0; r < 4; ++r) {
                float s = hreg[0][r] + hreg[1][r] + hreg[2][r] + hreg[3][r];
                float ss = hreg[0][r] * hreg[0][r] + hreg[1][r] * hreg[1][r]
                         + hreg[2][r] * hreg[2][r] + hreg[3][r] * hreg[3][r];
                #pragma unroll
                for (int o = 1; o < 16; o <<= 1) { s += __shfl_xor(s, o); ss += __shfl_xor(ss, o); }
                if (l15 == 0) lnb[(Mt * 16 + quad * 4 + r) * 2 + (wave & 1)] = make_float2(s, ss);
            }
            __syncthreads();
            #pragma unroll
            for (int r = 0; r < 4; ++r) {
                int row = Mt * 16 + quad * 4 + r;
                float2 h0 = lnb[row * 2], h1 = lnb[row * 2 + 1];
                float mu = (h0.x + h1.x) * (1.0f / 128.0f);
                float var = (h0.y + h1.y) * (1.0f / 128.0f) - mu * mu;
                float rs = rsqrtf(var + 1e-5f);
                #pragma unroll
                for (int s = 0; s < 4; ++s) {
                    int col = s * 32 + nl;
                    sm.T2[sidx(row, col)] = f2bf((hreg[s][r] - mu) * rs * lg[col] + lb[col]);
                }
            }
        }
        __syncthreads();

        // --- Clifford MLP: 4 K-chunks, C1 ping-pong T1/T2-alt buffer, C2 acc ---
        {
            short8 a_x[4]; loadA(sm.T2, mrow, quad, a_x);
            f32x4 acc2[4];
            #pragma unroll
            for (int s = 0; s < 4; ++s) acc2[s] = (f32x4){0.f, 0.f, 0.f, 0.f};
            for (int j = 0; j < 4; ++j) {
                ushort_t* buf = (j & 1) ? sm.T2 : sm.T1;
                f32x4 acc[4];
                mfma4(a_x, wl + IMG_C1 + j * 16384, nl, quad, acc);
                #pragma unroll
                for (int s = 0; s < 4; ++s) {
                    int col = s * 32 + nl; float bv = c1b[j * H_ + col];
                    #pragma unroll
                    for (int r = 0; r < 4; ++r)
                        buf[sidx(Mt * 16 + quad * 4 + r, col)] = f2bf(siluf(acc[s][r] + bv));
                }
                __syncthreads();
                short8 a_t[4]; loadA(buf, mrow, quad, a_t);
                const ushort_t* img = wl + IMG_C2 + j * 16384;
                #pragma unroll
                for (int s = 0; s < 4; ++s) {
                    #pragma unroll
                    for (int kc = 0; kc < 4; ++kc) {
                        short8 bv = *(const short8*)(img + s * 4096 + nl * 128 + (kc * 4 + quad) * 8);
                        acc2[s] = __builtin_amdgcn_mfma_f32_16x16x32_bf16(a_t[kc], bv, acc2[s], 0, 0, 0);
                    }
                }
            }
            // h_next = fused + mlp + c2b -> hreg + Ha
            #pragma unroll
            for (int s = 0; s < 4; ++s) {
                int col = s * 32 + nl; float bv = c2b[col];
                #pragma unroll
                for (int r = 0; r < 4; ++r) {
                    float v = hreg[s][r] + acc2[s][r] + bv;
                    hreg[s][r] = v;
                    sm.Ha[sidx(Mt * 16 + quad * 4 + r, col)] = f2bf(v);
                }
            }
        }
        __syncthreads();
    }

    // ---- head ----
    {
        short8 a_h[4]; loadA(sm.Ha, mrow, quad, a_h);
        f32x4 acc[4];
        mfma4(a_h, wimg + IMG_FO, nl, quad, acc);
        #pragma unroll
        for (int s = 0; s < 4; ++s) {
            int col = s * 32 + nl; float bv = fo_b1[col];
            #pragma unroll
            for (int r = 0; r < 4; ++r)
                sm.T1[sidx(Mt * 16 + quad * 4 + r, col)] = f2bf(siluf(acc[s][r] + bv));
        }
    }
    __syncthreads();
    if (tid < N_ * 3) {
        int n = tid / 3, j = tid - n * 3;
        float s = fo_b2[j];
        for (int c = 0; c < H_; ++c)
            s = fmaf(bf2f(sm.T1[sidx(n, c)]), fo_W2[c * 3 + j], s);
        out[b * N_ * 3 + tid] = s;
    }
}

extern "C" void kernel_launch(void* const* d_in, const int* in_sizes, int n_in,
                              void* d_out, int out_size, void* d_ws, size_t ws_size,
                              hipStream_t stream) {
    (void)in_sizes; (void)n_in; (void)out_size; (void)ws_size;
    convert_weights<<<248, 256, 0, stream>>>(
        (const float*)d_in[5], (const float*)d_in[7], (const float*)d_in[9],
        (const float*)d_in[12], (const float*)d_in[16], (const float*)d_in[18],
        (const float*)d_in[10], (const float*)d_in[20], (ushort_t*)d_ws);
    md17_fused_kernel<<<B_, NT, 0, stream>>>(
        (const float*)d_in[0], (const int*)d_in[1],
        (const float*)d_in[2], (const float*)d_in[3], (const float*)d_in[4],
        (const float*)d_in[6], (const float*)d_in[8],
        (const float*)d_in[11], (const float*)d_in[13],
        (const float*)d_in[14], (const float*)d_in[15],
        (const float*)d_in[17], (const float*)d_in[19],
        (const float*)d_in[21],
        (const float*)d_in[22], (const float*)d_in[23],
        (char*)d_ws, (float*)d_out);
}

// Round 7
// 1680.889 us; speedup vs baseline: 4.2299x; 1.0109x over previous
//
#include <hip/hip_runtime.h>

typedef unsigned short ushort_t;
typedef unsigned int uint_t;
typedef unsigned long long ull_t;
typedef __attribute__((ext_vector_type(8))) short short8;
typedef __attribute__((ext_vector_type(4))) float f32x4;

#define B_ 1024
#define N_ 64
#define H_ 128
#define NT 512

// bf16 weight-image element offsets
#define IMG_WI 0
#define IMG_WJ 16384
#define IMG_UW 32768
#define IMG_GS 49152
#define IMG_FT 65536
#define IMG_FB 81920
#define IMG_C1 98304
#define IMG_C2 163840
#define IMG_GMT 229376
#define IMG_RW 245760
#define IMG_L 249856
#define IMG_FO 999424

__device__ __forceinline__ ushort_t f2bf(float f) {
    uint_t u = __float_as_uint(f);
    return (ushort_t)((u + 0x7fffu + ((u >> 16) & 1u)) >> 16);
}
__device__ __forceinline__ float bf2f(ushort_t u) {
    union { uint_t i; float f; } v; v.i = ((uint_t)u) << 16; return v.f;
}
__device__ __forceinline__ float siluf(float x) { return x / (1.0f + __expf(-x)); }

// LDS swizzle: 16B-chunk c of row m stored at chunk c ^ (m&7)
__device__ __forceinline__ int sidx(int m, int k) {
    return m * H_ + (((k >> 3) ^ (m & 7)) << 3) + (k & 7);
}
__device__ __forceinline__ int fragoff(int m, int ch) {
    return m * H_ + ((ch ^ (m & 7)) << 3);
}

// ========== preamble: f32 weights -> transposed bf16 images ================
extern "C" __global__ __launch_bounds__(256)
void convert_weights(const float* __restrict__ msg_W, const float* __restrict__ upd_W,
                     const float* __restrict__ gself_W, const float* __restrict__ fus_W,
                     const float* __restrict__ cb_W1, const float* __restrict__ cb_W2,
                     const float* __restrict__ gmean_W, const float* __restrict__ fo_W1,
                     ushort_t* __restrict__ wimg)
{
    const int g = blockIdx.x;
    if (g >= 244) {                      // fo_W1: 4 stages
        int st = g - 244;
        ushort_t* dst = wimg + IMG_FO + st * 4096;
        for (int e = 0; e < 16; ++e) {
            int q = threadIdx.x * 16 + e;
            int n = q >> 7, k = q & 127;
            dst[q] = f2bf(fo_W1[(size_t)k * 128 + st * 32 + n]);
        }
        return;
    }
    const int l = g / 61, r = g - l * 61;
    ushort_t* base = wimg + l * IMG_L;
    if (r == 60) {                       // rW pad image: 4 sub-stages [32f][32k]
        const float* W = msg_W + l * 35328 + 256 * 128;
        ushort_t* dst = base + IMG_RW;
        for (int e = 0; e < 16; ++e) {
            int q = threadIdx.x * 16 + e;
            int sub = q >> 10, n = (q >> 5) & 31, k = q & 31;
            dst[q] = f2bf(k < 20 ? W[(size_t)k * 128 + sub * 32 + n] : 0.0f);
        }
        return;
    }
    const float* W; int ld = 128, k0 = 0, c0, off, st;
    if      (r < 4)  { W = msg_W + l * 35328;            st = r;      off = IMG_WI;  c0 = st * 32; }
    else if (r < 8)  { W = msg_W + l * 35328;  k0 = 128; st = r - 4;  off = IMG_WJ;  c0 = st * 32; }
    else if (r < 12) { W = upd_W + l * 16384;            st = r - 8;  off = IMG_UW;  c0 = st * 32; }
    else if (r < 16) { W = gself_W + l * 16384;          st = r - 12; off = IMG_GS;  c0 = st * 32; }
    else if (r < 20) { W = fus_W + l * 32768;            st = r - 16; off = IMG_FT;  c0 = st * 32; }
    else if (r < 24) { W = fus_W + l * 32768;  k0 = 128; st = r - 20; off = IMG_FB;  c0 = st * 32; }
    else if (r < 40) { W = cb_W1 + l * 65536;  ld = 512; st = r - 24; off = IMG_C1;  c0 = st * 32; }
    else if (r < 56) { int j = (r - 40) >> 2; W = cb_W2 + l * 65536; k0 = j * 128;
                       st = r - 40; off = IMG_C2; c0 = ((r - 40) & 3) * 32; }
    else             { W = gmean_W + l * 16384;          st = r - 56; off = IMG_GMT; c0 = st * 32; }
    ushort_t* dst = base + off + st * 4096;
    for (int e = 0; e < 16; ++e) {
        int q = threadIdx.x * 16 + e;
        int n = q >> 7, k = q & 127;
        dst[q] = f2bf(W[(size_t)(k0 + k) * ld + c0 + n]);
    }
}

// ========== main fused kernel ==============================================
struct __align__(16) Smem {
    ushort_t Ha[N_ * H_];   // 16384B  h bf16 swizzled (never clobbered mid-layer)
    ushort_t T1[N_ * H_];   // 16384B
    ushort_t T2[N_ * H_];   // 16384B
    float spos[N_ * 3];     //   768
    float env[1024];        //  4096  envelope per (n,k)
    float d[1024];          //  4096  distance per (n,k) (phase A: d2)
    float hmean[H_];        //   512
    float gvec[H_];         //   512
    float scratch[512];     //  2048  hmean partials / LN (sum,ss)
    ushort_t idx[1024];     //  2048
};                          // total 63232 B -> 2 blocks/CU

__device__ __forceinline__ void mfma4(const short8 a[4], const ushort_t* __restrict__ img,
                                      int nl, int quad, f32x4 acc[4])
{
    short8 bv[16];
    #pragma unroll
    for (int s = 0; s < 4; ++s)
        #pragma unroll
        for (int kc = 0; kc < 4; ++kc)
            bv[s * 4 + kc] = *(const short8*)(img + s * 4096 + nl * 128 + (kc * 4 + quad) * 8);
    #pragma unroll
    for (int s = 0; s < 4; ++s) {
        f32x4 c = {0.f, 0.f, 0.f, 0.f};
        #pragma unroll
        for (int kc = 0; kc < 4; ++kc)
            c = __builtin_amdgcn_mfma_f32_16x16x32_bf16(a[kc], bv[s * 4 + kc], c, 0, 0, 0);
        acc[s] = c;
    }
}
__device__ __forceinline__ void loadA(const ushort_t* __restrict__ X, int mrow, int quad, short8 a[4]) {
    #pragma unroll
    for (int kc = 0; kc < 4; ++kc) a[kc] = *(const short8*)&X[fragoff(mrow, kc * 4 + quad)];
}

extern "C" __global__ __launch_bounds__(NT, 4)
void md17_fused_kernel(
    const float* __restrict__ positions, const int* __restrict__ atomic_numbers,
    const float* __restrict__ atom_embed, const float* __restrict__ pos_W,
    const float* __restrict__ pos_b,
    const float* __restrict__ msg_b, const float* __restrict__ upd_b,
    const float* __restrict__ g_b, const float* __restrict__ fus_b,
    const float* __restrict__ ln_g, const float* __restrict__ ln_b,
    const float* __restrict__ cb_b1, const float* __restrict__ cb_b2,
    const float* __restrict__ fo_b1,
    const float* __restrict__ fo_W2, const float* __restrict__ fo_b2,
    char* __restrict__ ws, float* __restrict__ out)
{
    __shared__ Smem sm;
    const int b = blockIdx.x;
    const int tid = threadIdx.x;
    const int wave = tid >> 6, lane = tid & 63;
    const int quad = lane >> 4, l15 = lane & 15;
    const int Mt = wave >> 1;
    const int mrow = Mt * 16 + l15;
    const int nl = (wave & 1) * 16 + l15;

    const ushort_t* wimg = (const ushort_t*)ws;

    // rbf centers for this lane's k-dims (quad*8+j), double-rounded like np
    float ccv[8];
    #pragma unroll
    for (int j = 0; j < 8; ++j)
        ccv[j] = (float)((double)(quad * 8 + j) * (5.0 / 19.0));

    for (int t = tid; t < N_ * 3; t += NT) sm.spos[t] = positions[b * N_ * 3 + t];
    __syncthreads();

    // ---- kNN (validated): wave w -> atoms w*8..w*8+7 ----
    {
        const int m = lane;
        for (int a = 0; a < 8; ++a) {
            int n = wave * 8 + a;
            float dx = __fsub_rn(sm.spos[n * 3 + 0], sm.spos[m * 3 + 0]);
            float dy = __fsub_rn(sm.spos[n * 3 + 1], sm.spos[m * 3 + 1]);
            float dz = __fsub_rn(sm.spos[n * 3 + 2], sm.spos[m * 3 + 2]);
            float d2 = __fadd_rn(__fadd_rn(__fmul_rn(dx, dx), __fmul_rn(dy, dy)), __fmul_rn(dz, dz));
            if (m == n) d2 = 1e30f;
            for (int k = 0; k < 16; ++k) {
                float dmin = d2;
                #pragma unroll
                for (int o = 1; o < 64; o <<= 1) dmin = fminf(dmin, __shfl_xor(dmin, o));
                ull_t mask = __ballot(d2 == dmin);
                int widx = __ffsll(mask) - 1;   // lowest index on ties (= top_k)
                if (lane == widx) d2 = 1e30f;
                if (lane == k) { sm.idx[n * 16 + k] = (ushort_t)widx; sm.d[n * 16 + k] = dmin; }
            }
        }
    }
    __syncthreads();

    // ---- d2 -> d, env ----
    for (int p = tid; p < 1024; p += NT) {
        float dd = sqrtf(fmaxf(sm.d[p], 1e-12f));
        float e = 0.0f;
        if (dd < 5.0f) e = 0.5f * (cosf(3.14159265358979323846f * dd * 0.2f) + 1.0f);
        sm.d[p] = dd;
        sm.env[p] = e;
    }

    // ---- embeddings -> hreg (f32 C-layout) + Ha ----
    float hreg[4][4];
    {
        int types[4];
        #pragma unroll
        for (int r = 0; r < 4; ++r) types[r] = atomic_numbers[b * N_ + Mt * 16 + quad * 4 + r];
        #pragma unroll
        for (int s = 0; s < 4; ++s) {
            int col = s * 32 + nl;
            #pragma unroll
            for (int r = 0; r < 4; ++r) {
                int row = Mt * 16 + quad * 4 + r;
                float v;
                if (col < 32) v = atom_embed[types[r] * 32 + col];
                else {
                    int j = col - 32;
                    v = pos_b[j];
                    #pragma unroll
                    for (int c = 0; c < 3; ++c)
                        v = fmaf(sm.spos[row * 3 + c], pos_W[c * 96 + j], v);
                }
                hreg[s][r] = v;
                sm.Ha[sidx(row, col)] = f2bf(v);
            }
        }
    }
    __syncthreads();

    for (int l = 0; l < 4; ++l) {
        const ushort_t* wl = wimg + l * IMG_L;
        const float* mb  = msg_b + l * H_;
        const float* ub  = upd_b + l * H_;
        const float* gb  = g_b + l * H_;
        const float* fb  = fus_b + l * H_;
        const float* lg  = ln_g + l * H_;
        const float* lb  = ln_b + l * H_;
        const float* c1b = cb_b1 + l * 4 * H_;
        const float* c2b = cb_b2 + l * H_;

        // --- hmean (parallel partial) + gvec ---
        {
            int seg = tid >> 7, f = tid & 127;
            float s = 0.f;
            for (int n = seg * 16; n < seg * 16 + 16; ++n) s += bf2f(sm.Ha[sidx(n, f)]);
            sm.scratch[seg * 128 + f] = s;
        }
        __syncthreads();
        if (tid < H_) {
            sm.hmean[tid] = (sm.scratch[tid] + sm.scratch[128 + tid]
                           + sm.scratch[256 + tid] + sm.scratch[384 + tid]) * (1.0f / 64.0f);
        }
        __syncthreads();
        if (tid < H_) {
            float s = gb[tid];
            const ushort_t* wrow = wl + IMG_GMT + tid * 128;
            for (int c = 0; c < 128; c += 8) {
                short8 w = *(const short8*)(wrow + c);
                #pragma unroll
                for (int i = 0; i < 8; ++i) s = fmaf(sm.hmean[c + i], bf2f((ushort_t)w[i]), s);
            }
            sm.gvec[tid] = s;
        }

        // --- WI -> T1 (+mb), WJ -> T2 ---
        short8 a_h[4]; loadA(sm.Ha, mrow, quad, a_h);
        {
            f32x4 acc[4];
            mfma4(a_h, wl + IMG_WI, nl, quad, acc);
            #pragma unroll
            for (int s = 0; s < 4; ++s) {
                int col = s * 32 + nl; float bv = mb[col];
                #pragma unroll
                for (int r = 0; r < 4; ++r)
                    sm.T1[sidx(Mt * 16 + quad * 4 + r, col)] = f2bf(acc[s][r] + bv);
            }
            mfma4(a_h, wl + IMG_WJ, nl, quad, acc);
            #pragma unroll
            for (int s = 0; s < 4; ++s) {
                int col = s * 32 + nl;
                #pragma unroll
                for (int r = 0; r < 4; ++r)
                    sm.T2[sidx(Mt * 16 + quad * 4 + r, col)] = f2bf(acc[s][r]);
            }
        }
        __syncthreads();

        // --- msum: barrier-free, wave-local; rproj consumed from accumulator ---
        {
            const ushort_t* imgrw = wl + IMG_RW;
            short8 brw[4];
            #pragma unroll
            for (int s = 0; s < 4; ++s)
                brw[s] = *(const short8*)(imgrw + s * 1024 + nl * 32 + quad * 8);
            for (int g = 0; g < 16; ++g) {
                int n = g * 4 + Mt;                  // whole wave: one atom
                float dd = sm.d[(g * 64 + Mt * 16 + l15)];
                short8 arb;
                #pragma unroll
                for (int j = 0; j < 8; ++j) {
                    float t2 = dd - ccv[j];
                    float rv = __expf(-10.0f * t2 * t2);
                    arb[j] = (short)((quad * 8 + j) < 20 ? f2bf(rv) : (ushort_t)0);
                }
                #pragma unroll
                for (int s = 0; s < 4; ++s) {
                    f32x4 c = {0.f, 0.f, 0.f, 0.f};
                    c = __builtin_amdgcn_mfma_f32_16x16x32_bf16(arb, brw[s], c, 0, 0, 0);
                    int col = s * 32 + nl;
                    float ai = bf2f(sm.T1[sidx(n, col)]);
                    float acc = 0.f;
                    #pragma unroll
                    for (int r = 0; r < 4; ++r) {
                        int k = quad * 4 + r;
                        int j = sm.idx[n * 16 + k];
                        float e = sm.env[n * 16 + k];
                        float gm = bf2f(sm.T2[sidx(j, col)]);
                        acc = fmaf(siluf(ai + gm + c[r]), e, acc);
                    }
                    acc += __shfl_xor(acc, 16);
                    acc += __shfl_xor(acc, 32);
                    if (quad == 0) sm.T1[sidx(n, col)] = f2bf(acc);
                }
            }
        }
        __syncthreads();

        // --- UW (A=msum) -> T2 local ; GS (A=Ha) -> T1 glob ---
        {
            short8 a_m[4]; loadA(sm.T1, mrow, quad, a_m);
            __syncthreads();               // all T1 reads done before overwrite
            f32x4 acc[4];
            mfma4(a_m, wl + IMG_UW, nl, quad, acc);
            #pragma unroll
            for (int s = 0; s < 4; ++s) {
                int col = s * 32 + nl; float bv = ub[col];
                #pragma unroll
                for (int r = 0; r < 4; ++r)
                    sm.T2[sidx(Mt * 16 + quad * 4 + r, col)] = f2bf(hreg[s][r] + siluf(acc[s][r] + bv));
            }
            mfma4(a_h, wl + IMG_GS, nl, quad, acc);
            #pragma unroll
            for (int s = 0; s < 4; ++s) {
                float gv = sm.gvec[s * 32 + nl];
                #pragma unroll
                for (int r = 0; r < 4; ++r)
                    sm.T1[sidx(Mt * 16 + quad * 4 + r, s * 32 + nl)] = f2bf(siluf(acc[s][r] + gv));
            }
        }
        __syncthreads();

        // --- fused = silu([local|glob] @ [FT;FB] + fb) -> hreg ---
        {
            short8 a_loc[4], a_gl[4];
            loadA(sm.T2, mrow, quad, a_loc);
            loadA(sm.T1, mrow, quad, a_gl);
            #pragma unroll
            for (int s = 0; s < 4; ++s) {
                f32x4 c = {0.f, 0.f, 0.f, 0.f};
                #pragma unroll
                for (int kc = 0; kc < 4; ++kc) {
                    short8 bv = *(const short8*)(wl + IMG_FT + s * 4096 + nl * 128 + (kc * 4 + quad) * 8);
                    c = __builtin_amdgcn_mfma_f32_16x16x32_bf16(a_loc[kc], bv, c, 0, 0, 0);
                }
                #pragma unroll
                for (int kc = 0; kc < 4; ++kc) {
                    short8 bv = *(const short8*)(wl + IMG_FB + s * 4096 + nl * 128 + (kc * 4 + quad) * 8);
                    c = __builtin_amdgcn_mfma_f32_16x16x32_bf16(a_gl[kc], bv, c, 0, 0, 0);
                }
                int col = s * 32 + nl; float bv = fb[col];
                #pragma unroll
                for (int r = 0; r < 4; ++r) hreg[s][r] = siluf(c[r] + bv);
            }
        }
        __syncthreads();

        // --- LN(hreg) -> T2 ---
        {
            float2* lnb = (float2*)sm.scratch;
            #pragma unroll
            for (int r = 0; r < 4; ++r) {
                float s = hreg[0][r] + hreg[1][r] + hreg[2][r] + hreg[3][r];
                float ss = hreg[0][r] * hreg[0][r] + hreg[1][r] * hreg[1][r]
                         + hreg[2][r] * hreg[2][r] + hreg[3][r] * hreg[3][r];
                #pragma unroll
                for (int o = 1; o < 16; o <<= 1) { s += __shfl_xor(s, o); ss += __shfl_xor(ss, o); }
                if (l15 == 0) lnb[(Mt * 16 + quad * 4 + r) * 2 + (wave & 1)] = make_float2(s, ss);
            }
            __syncthreads();
            #pragma unroll
            for (int r = 0; r < 4; ++r) {
                int row = Mt * 16 + quad * 4 + r;
                float2 h0 = lnb[row * 2], h1 = lnb[row * 2 + 1];
                float mu = (h0.x + h1.x) * (1.0f / 128.0f);
                float var = (h0.y + h1.y) * (1.0f / 128.0f) - mu * mu;
                float rs = rsqrtf(var + 1e-5f);
                #pragma unroll
                for (int s = 0; s < 4; ++s) {
                    int col = s * 32 + nl;
                    sm.T2[sidx(row, col)] = f2bf((hreg[s][r] - mu) * rs * lg[col] + lb[col]);
                }
            }
        }
        __syncthreads();

        // --- Clifford MLP: 4 K-chunks, ping-pong C1 buffer, persistent C2 acc ---
        {
            short8 a_x[4]; loadA(sm.T2, mrow, quad, a_x);
            f32x4 acc2[4];
            #pragma unroll
            for (int s = 0; s < 4; ++s) acc2[s] = (f32x4){0.f, 0.f, 0.f, 0.f};
            for (int j = 0; j < 4; ++j) {
                ushort_t* buf = (j & 1) ? sm.T2 : sm.T1;
                f32x4 acc[4];
                mfma4(a_x, wl + IMG_C1 + j * 16384, nl, quad, acc);
                #pragma unroll
                for (int s = 0; s < 4; ++s) {
                    int col = s * 32 + nl; float bv = c1b[j * H_ + col];
                    #pragma unroll
                    for (int r = 0; r < 4; ++r)
                        buf[sidx(Mt * 16 + quad * 4 + r, col)] = f2bf(siluf(acc[s][r] + bv));
                }
                __syncthreads();
                short8 a_t[4]; loadA(buf, mrow, quad, a_t);
                const ushort_t* img = wl + IMG_C2 + j * 16384;
                #pragma unroll
                for (int s = 0; s < 4; ++s) {
                    #pragma unroll
                    for (int kc = 0; kc < 4; ++kc) {
                        short8 bv = *(const short8*)(img + s * 4096 + nl * 128 + (kc * 4 + quad) * 8);
                        acc2[s] = __builtin_amdgcn_mfma_f32_16x16x32_bf16(a_t[kc], bv, acc2[s], 0, 0, 0);
                    }
                }
            }
            #pragma unroll
            for (int s = 0; s < 4; ++s) {
                int col = s * 32 + nl; float bv = c2b[col];
                #pragma unroll
                for (int r = 0; r < 4; ++r) {
                    float v = hreg[s][r] + acc2[s][r] + bv;
                    hreg[s][r] = v;
                    sm.Ha[sidx(Mt * 16 + quad * 4 + r, col)] = f2bf(v);
                }
            }
        }
        __syncthreads();
    }

    // ---- head ----
    {
        short8 a_h2[4]; loadA(sm.Ha, mrow, quad, a_h2);
        f32x4 acc[4];
        mfma4(a_h2, wimg + IMG_FO, nl, quad, acc);
        #pragma unroll
        for (int s = 0; s < 4; ++s) {
            int col = s * 32 + nl; float bv = fo_b1[col];
            #pragma unroll
            for (int r = 0; r < 4; ++r)
                sm.T1[sidx(Mt * 16 + quad * 4 + r, col)] = f2bf(siluf(acc[s][r] + bv));
        }
    }
    __syncthreads();
    if (tid < N_ * 3) {
        int n = tid / 3, j = tid - n * 3;
        float s = fo_b2[j];
        for (int c = 0; c < H_; ++c)
            s = fmaf(bf2f(sm.T1[sidx(n, c)]), fo_W2[c * 3 + j], s);
        out[b * N_ * 3 + tid] = s;
    }
}

extern "C" void kernel_launch(void* const* d_in, const int* in_sizes, int n_in,
                              void* d_out, int out_size, void* d_ws, size_t ws_size,
                              hipStream_t stream) {
    (void)in_sizes; (void)n_in; (void)out_size; (void)ws_size;
    convert_weights<<<248, 256, 0, stream>>>(
        (const float*)d_in[5], (const float*)d_in[7], (const float*)d_in[9],
        (const float*)d_in[12], (const float*)d_in[16], (const float*)d_in[18],
        (const float*)d_in[10], (const float*)d_in[20], (ushort_t*)d_ws);
    md17_fused_kernel<<<B_, NT, 0, stream>>>(
        (const float*)d_in[0], (const int*)d_in[1],
        (const float*)d_in[2], (const float*)d_in[3], (const float*)d_in[4],
        (const float*)d_in[6], (const float*)d_in[8],
        (const float*)d_in[11], (const float*)d_in[13],
        (const float*)d_in[14], (const float*)d_in[15],
        (const float*)d_in[17], (const float*)d_in[19],
        (const float*)d_in[21],
        (const float*)d_in[22], (const float*)d_in[23],
        (char*)d_ws, (float*)d_out);
}